// Round 18
// baseline (2168.452 us; speedup 1.0000x reference)
//
#include <hip/hip_runtime.h>
#include <stdint.h>
#include <math.h>

#define DEVI __device__ __forceinline__

typedef __attribute__((ext_vector_type(8))) _Float16 f16x8;
typedef __attribute__((ext_vector_type(4))) float f32x4;

#define LO_SCALE 2048.0f
#define LO_INV (1.0f / 2048.0f)
#define LO_INV_D (1.0 / 2048.0)
// int32 fixed-point aggregation at 2^22, quantized/read back through double:
// per-message error <= 1.2e-7 absolute; integer sum is order-exact.
#define AGG_SCALE_D 4194304.0
#define AGG_INV_D (1.0 / 4194304.0)

DEVI unsigned short f2h(float f) {
  union { _Float16 h; unsigned short u; } v; v.h = (_Float16)f; return v.u;
}
DEVI float h2f(unsigned short u) {
  union { unsigned short u; _Float16 h; } v; v.u = u; return (float)v.h;
}
DEVI unsigned short loPart(float v, unsigned short hi) {
  return f2h((v - h2f(hi)) * LO_SCALE);
}
DEVI f32x4 mfma16(f16x8 a, f16x8 b, f32x4 c) {
  return __builtin_amdgcn_mfma_f32_16x16x32_f16(a, b, c, 0, 0, 0);
}
// Full 4-term pair product: acc += Ah*Bh ; accx += Ah*Bl + Al*Bh ; accy += Al*Bl
// (accx scaled x2048, accy x2048^2). Combine in f64: ~f32-exact GEMM.
DEVI void mfma4(f16x8 ah, f16x8 al, f16x8 bh, f16x8 bl,
                f32x4& acc, f32x4& accx, f32x4& accy) {
  acc  = mfma16(ah, bh, acc);
  accx = mfma16(ah, bl, accx);
  accx = mfma16(al, bh, accx);
  accy = mfma16(al, bl, accy);
}
DEVI float combine3(float a, float ax, float ay, float b) {
  return (float)((double)a + ((double)ax + (double)ay * LO_INV_D) * LO_INV_D + (double)b);
}
// swizzled element offset inside one [rows][128] fp16 tile (row stride 256B).
DEVI int swz(int row, int col) { return row * 128 + (col ^ ((row & 7) << 3)); }

struct KParams {
  const unsigned short* w1h; const unsigned short* w1l;
  const unsigned short* w2h; const unsigned short* w2l;
  const float* b1; const float* b2; const float* g; const float* be;
  const float* srcA;                 // ENC: x/e
  const unsigned short* xhi;         // fp16 hi mirror of xh
  const unsigned short* xlo;         // fp16 lo mirror (x2048)
  float* xf;                         // xh f32 master
  float* ef;                         // eh f32 master
  unsigned short* xhi_out; unsigned short* xlo_out;
  const int* rowi; const int* coli;
  int* aggi;                         // [N,128] int32 2^22 fixed-point aggregate
  float* out;
  const float* w2f; const float* b2f;  // decoder layer-2 (f32)
  int nrows; int kin;
};

struct RepackItem { const float* src; unsigned short* dst; int K; int Kt; };
struct RepackParams { RepackItem it[17]; };

// Pack W [K][128] f32 -> fp16 hi/lo MFMA B-fragments. hi at [0, Kt*8*512),
// lo (x2048) at [Kt*8*512, 2*Kt*8*512).
__global__ __launch_bounds__(256) void repack_kernel(RepackParams rp) {
  const RepackItem w = rp.it[blockIdx.y];
  const int f = blockIdx.x;
  if (f >= w.Kt * 8) return;
  const int kt = f >> 3, nt = f & 7;
  const size_t loOff = (size_t)w.Kt * 8 * 512;
  for (int s = threadIdx.x; s < 512; s += 256) {
    int ln = s >> 3, j = s & 7;
    int k = kt * 32 + ((ln >> 4) << 3) + j;
    int c = nt * 16 + (ln & 15);
    float v = (k < w.K) ? w.src[(size_t)k * 128 + c] : 0.f;
    unsigned short hi = f2h(v);
    w.dst[(size_t)f * 512 + s] = hi;
    w.dst[loOff + (size_t)f * 512 + s] = loPart(v, hi);
  }
}

// Modes: 0=node-encoder 1=edge-encoder 2=edge-processor 3=node-processor 4=decoder
// MODE 2 (col-split, 1024 threads / 4 waves per SIMD): 16 waves over 64 edges.
// wave -> (vrt = wave>>3: 0=msg 1=edge-update, band = (wave>>1)&3: 16-row band,
// ntg = wave&1: 64-col half). Each wave: 16 rows x 64 cols -> 12 f32x4
// accumulators (48 VGPR, no spill at the 128-VGPR/4-wave cap). Weights
// double-buffered in LDS (32KB). h1 hi/lo in LDS (64KB) + 4KB f64 LN-exchange.
// LN row stats combine the two col-halves via LDS in fixed (ntg0+ntg1) order ->
// deterministic. GEMM bits identical to R16. [R17 bug fixed: layer-2 staging
// guard must be kt<3 so W2 step 15 is staged for kt=3.]
template <int MODE>
__global__ __launch_bounds__((MODE == 2) ? 1024 : 256, (MODE == 2) ? 1 : 2)
void gnn_kernel(KParams p) {
  constexpr int NT = (MODE == 2) ? 1024 : 256;
  constexpr int REG = 8192;                        // elems per hi (or lo) region
  constexpr int NREG = (MODE == 2 || MODE == 3) ? 2 : 1;
  constexpr int NTL = (MODE == 2) ? 4 : 8;         // output col-blocks per wave
  __shared__ __align__(16) unsigned short stA[NREG * 2 * REG];
  __shared__ __align__(16) unsigned short wbuf[(MODE == 2) ? 16384 : 1];  // 2 x 16KB
  __shared__ double lnbuf[(MODE == 2) ? 512 : 1];
  __shared__ float w2s[(MODE == 4) ? 392 : 1];

  const int tid = threadIdx.x;
  const int lane = tid & 63;
  const int wave = tid >> 6;
  const int w4 = (MODE == 2) ? ((wave >> 1) & 3) : wave;  // 16-row band index
  const int vrt = (MODE == 2) ? (wave >> 3) : 0;   // variant: 0=msg 1=edge-update
  const int ntg = (MODE == 2) ? (wave & 1) : 0;    // col half
  const int cb = ntg * 4;                          // col-block base (nt units)
  const int r0 = blockIdx.x * 64;
  const int l15 = lane & 15;
  const int lg = lane >> 4;

  auto HI = [&](int t) { return stA + 2 * t * REG; };
  auto LO = [&](int t) { return stA + 2 * t * REG + REG; };

  // stage one 16KB weight step (4096 hi + 4096 lo elems) into wbuf[buf]
  auto stageW = [&](int s, int buf) {
    const unsigned short* h = (s < 12) ? p.w1h + s * 4096 : p.w2h + (s - 12) * 4096;
    const unsigned short* l = (s < 12) ? p.w1l + s * 4096 : p.w2l + (s - 12) * 4096;
    for (int i = tid; i < 1024; i += NT) {
      *(f16x8*)&wbuf[buf * 8192 + i * 8] =
          *(const f16x8*)((i < 512) ? h + i * 8 : l + (i - 512) * 8);
    }
  };

  // ---------------- stage inputs (fp16 hi/lo, swizzled) — not MODE 2 ----------
  if constexpr (MODE == 3) {
    for (int s = tid; s < 1024; s += NT) {
      int row = s >> 4, cc = (s & 15) * 8;
      int n = r0 + row;
      int off = swz(row, cc);
      if (n < p.nrows) {
        const int* ap = p.aggi + (size_t)n * 128 + cc;
        union { unsigned short u[8]; f16x8 v; } th, tl;
#pragma unroll
        for (int j = 0; j < 8; j++) {
          float v = (float)((double)ap[j] * AGG_INV_D);   // exact int->double->f32
          th.u[j] = f2h(v); tl.u[j] = loPart(v, th.u[j]);
        }
        *(f16x8*)&HI(0)[off] = th.v; *(f16x8*)&LO(0)[off] = tl.v;
        *(f16x8*)&HI(1)[off] = *(const f16x8*)(p.xhi + (size_t)n * 128 + cc);
        *(f16x8*)&LO(1)[off] = *(const f16x8*)(p.xlo + (size_t)n * 128 + cc);
      } else {
        f16x8 z = {0,0,0,0,0,0,0,0};
        *(f16x8*)&HI(0)[off] = z; *(f16x8*)&LO(0)[off] = z;
        *(f16x8*)&HI(1)[off] = z; *(f16x8*)&LO(1)[off] = z;
      }
    }
  } else if constexpr (MODE == 0 || MODE == 1) {
    for (int s = tid; s < 256; s += NT) {
      int row = s >> 2, cc = (s & 3) * 8;
      int n = r0 + row;
      union { unsigned short u[8]; f16x8 v; } th, tl;
#pragma unroll
      for (int j = 0; j < 8; j++) {
        int k = cc + j;
        float v = (n < p.nrows && k < p.kin) ? p.srcA[(size_t)n * p.kin + k] : 0.f;
        th.u[j] = f2h(v); tl.u[j] = loPart(v, th.u[j]);
      }
      int off = swz(row, cc);
      *(f16x8*)&HI(0)[off] = th.v; *(f16x8*)&LO(0)[off] = tl.v;
    }
  } else if constexpr (MODE == 4) {
    for (int s = tid; s < 1024; s += NT) {
      int row = s >> 4, cc = (s & 15) * 8;
      int n = r0 + row;
      int off = swz(row, cc);
      f16x8 z = {0,0,0,0,0,0,0,0};
      if (n < p.nrows) {
        *(f16x8*)&HI(0)[off] = *(const f16x8*)(p.xhi + (size_t)n * 128 + cc);
        *(f16x8*)&LO(0)[off] = *(const f16x8*)(p.xlo + (size_t)n * 128 + cc);
      } else { *(f16x8*)&HI(0)[off] = z; *(f16x8*)&LO(0)[off] = z; }
    }
    for (int s = tid; s < 387; s += NT) w2s[s] = (s < 384) ? p.w2f[s] : p.b2f[s - 384];
  } else {  // MODE 2: weight prologue only
    stageW(0, 0);
  }
  __syncthreads();

  // ---------------- layer 1 (K = K1T*32) ----------------
  constexpr int K1T = (MODE == 2) ? 12 : (MODE == 3) ? 8 : (MODE == 4) ? 4 : 1;
  const f32x4 zz = {0.f, 0.f, 0.f, 0.f};
  f32x4 acc1[NTL], acc1x[NTL], acc1y[NTL];
#pragma unroll
  for (int nt = 0; nt < NTL; nt++) { acc1[nt] = zz; acc1x[nt] = zz; acc1y[nt] = zz; }
  const int arow = w4 * 16 + l15;
  const int acol = lg << 3;

  if constexpr (MODE == 2) {
    // Per-lane direct-from-global A operands. Lane's A row = edge r0+arow.
    const int ridx = r0 + arow;
    const int ec = (ridx < p.nrows) ? ridx : 0;   // clamped (outputs discarded)
    const int nc = p.coli[ec], nr = p.rowi[ec];
    // msg variant: [Xc, Xr, Ee] ; edge-update variant: [Xr, Xc, Ee]
    const unsigned short* aH = p.xhi + (size_t)(vrt ? nr : nc) * 128;
    const unsigned short* aL = p.xlo + (size_t)(vrt ? nr : nc) * 128;
    const unsigned short* bH = p.xhi + (size_t)(vrt ? nc : nr) * 128;
    const unsigned short* bL = p.xlo + (size_t)(vrt ? nc : nr) * 128;
    const float* ep = p.ef + (size_t)ec * 128;
#pragma unroll
    for (int kt = 0; kt < 12; kt++) {
      const int cur = kt & 1;
      stageW(kt + 1, cur ^ 1);   // W1[kt+1] or (kt=11) W2[0]
      const int kc = (kt & 3) * 32 + acol;
      f16x8 ah, al;
      if (kt < 4)      { ah = *(const f16x8*)(aH + kc); al = *(const f16x8*)(aL + kc); }
      else if (kt < 8) { ah = *(const f16x8*)(bH + kc); al = *(const f16x8*)(bL + kc); }
      else {
        union { unsigned short u[8]; f16x8 v; } th, tl;
#pragma unroll
        for (int j = 0; j < 8; j++) {
          float v = ep[kc + j];
          th.u[j] = f2h(v); tl.u[j] = loPart(v, th.u[j]);
        }
        ah = th.v; al = tl.v;
      }
#pragma unroll
      for (int nt = 0; nt < NTL; nt++) {
        f16x8 bh = *(const f16x8*)&wbuf[cur * 8192 + (cb + nt) * 512 + lane * 8];
        f16x8 bl = *(const f16x8*)&wbuf[cur * 8192 + 4096 + (cb + nt) * 512 + lane * 8];
        mfma4(ah, al, bh, bl, acc1[nt], acc1x[nt], acc1y[nt]);
      }
      __syncthreads();
    }
  } else {
#pragma unroll
    for (int kt = 0; kt < K1T; kt++) {
      int t = kt >> 2;
      int so = swz(arow, (kt & 3) * 32 + acol);
      f16x8 ah = *(const f16x8*)&HI(t)[so];
      f16x8 al = *(const f16x8*)&LO(t)[so];
#pragma unroll
      for (int nt = 0; nt < NTL; nt++) {
        f16x8 bh = *(const f16x8*)&p.w1h[(size_t)(kt * 8 + nt) * 512 + lane * 8];
        f16x8 bl = *(const f16x8*)&p.w1l[(size_t)(kt * 8 + nt) * 512 + lane * 8];
        mfma4(ah, al, bh, bl, acc1[nt], acc1x[nt], acc1y[nt]);
      }
    }
  }

  // ---------------- h1 = relu(acc + b1) -> LDS hi/lo (region vrt) ----------
  float b1c[NTL];
#pragma unroll
  for (int nt = 0; nt < NTL; nt++) b1c[nt] = p.b1[(cb + nt) * 16 + l15];
#pragma unroll
  for (int nt = 0; nt < NTL; nt++) {
#pragma unroll
    for (int r = 0; r < 4; r++) {
      int row = w4 * 16 + (lg << 2) + r;
      int col = (cb + nt) * 16 + l15;
      int off = swz(row, col);
      float v = combine3(acc1[nt][r], acc1x[nt][r], acc1y[nt][r], b1c[nt]);
      v = v > 0.f ? v : 0.f;
      unsigned short hi = f2h(v);
      HI(vrt)[off] = hi; LO(vrt)[off] = loPart(v, hi);
    }
  }
  // MODE 2: layer-2 reads h1 cols written by the sibling ntg wave -> barrier.
  if constexpr (MODE == 2) __syncthreads();

  if constexpr (MODE != 4) {
    // ---------------- layer 2 (K=128 from h1 in LDS region vrt) ----------------
    f32x4 acc2[NTL], acc2x[NTL], acc2y[NTL];
#pragma unroll
    for (int nt = 0; nt < NTL; nt++) { acc2[nt] = zz; acc2x[nt] = zz; acc2y[nt] = zz; }
#pragma unroll
    for (int kt = 0; kt < 4; kt++) {
      if constexpr (MODE == 2) {
        const int cur = (12 + kt) & 1;
        if (kt < 3) stageW(13 + kt, cur ^ 1);   // W2[kt+1] (steps 13,14,15)
        int so = swz(arow, kt * 32 + acol);
        f16x8 ah = *(const f16x8*)&HI(vrt)[so];
        f16x8 al = *(const f16x8*)&LO(vrt)[so];
#pragma unroll
        for (int nt = 0; nt < NTL; nt++) {
          f16x8 bh = *(const f16x8*)&wbuf[cur * 8192 + (cb + nt) * 512 + lane * 8];
          f16x8 bl = *(const f16x8*)&wbuf[cur * 8192 + 4096 + (cb + nt) * 512 + lane * 8];
          mfma4(ah, al, bh, bl, acc2[nt], acc2x[nt], acc2y[nt]);
        }
        if (kt < 3) __syncthreads();
      } else {
        int so = swz(arow, kt * 32 + acol);
        f16x8 ah = *(const f16x8*)&HI(vrt)[so];
        f16x8 al = *(const f16x8*)&LO(vrt)[so];
#pragma unroll
        for (int nt = 0; nt < NTL; nt++) {
          f16x8 bh = *(const f16x8*)&p.w2h[(size_t)(kt * 8 + nt) * 512 + lane * 8];
          f16x8 bl = *(const f16x8*)&p.w2l[(size_t)(kt * 8 + nt) * 512 + lane * 8];
          mfma4(ah, al, bh, bl, acc2[nt], acc2x[nt], acc2y[nt]);
        }
      }
    }

    // ---------------- LayerNorm epilogue (f64 statistics) ----------------
    float b2c[NTL], gc[NTL], bec[NTL];
#pragma unroll
    for (int nt = 0; nt < NTL; nt++) {
      int c = (cb + nt) * 16 + l15;
      b2c[nt] = p.b2[c]; gc[nt] = p.g[c]; bec[nt] = p.be[c];
    }
    if constexpr (MODE == 2) {
      // cross-wave LN: each wave holds 64 of the row's 128 cols; exchange f64
      // partials through LDS; combine in fixed (ntg0 + ntg1) order.
      const int slot = ((vrt * 4 + w4) * 4 + lg) * 4;   // + r -> 0..127
      double ps[4] = {0.0, 0.0, 0.0, 0.0};
#pragma unroll
      for (int nt = 0; nt < NTL; nt++)
#pragma unroll
        for (int r = 0; r < 4; r++) {
          acc2[nt][r] = combine3(acc2[nt][r], acc2x[nt][r], acc2y[nt][r], b2c[nt]);
          ps[r] += (double)acc2[nt][r];
        }
#pragma unroll
      for (int r = 0; r < 4; r++)
#pragma unroll
        for (int m = 1; m < 16; m <<= 1) ps[r] += __shfl_xor(ps[r], m);
      if (l15 == 0) {
#pragma unroll
        for (int r = 0; r < 4; r++) lnbuf[(slot + r) * 2 + ntg] = ps[r];
      }
      __syncthreads();
      double mean[4];
#pragma unroll
      for (int r = 0; r < 4; r++)
        mean[r] = (lnbuf[(slot + r) * 2] + lnbuf[(slot + r) * 2 + 1]) * (1.0 / 128.0);
      double pv[4] = {0.0, 0.0, 0.0, 0.0};
#pragma unroll
      for (int nt = 0; nt < NTL; nt++)
#pragma unroll
        for (int r = 0; r < 4; r++) {
          double d = (double)acc2[nt][r] - mean[r];
          pv[r] += d * d;
        }
#pragma unroll
      for (int r = 0; r < 4; r++)
#pragma unroll
        for (int m = 1; m < 16; m <<= 1) pv[r] += __shfl_xor(pv[r], m);
      if (l15 == 0) {
#pragma unroll
        for (int r = 0; r < 4; r++) lnbuf[256 + (slot + r) * 2 + ntg] = pv[r];
      }
      __syncthreads();
      double rs[4];
#pragma unroll
      for (int r = 0; r < 4; r++) {
        double var = lnbuf[256 + (slot + r) * 2] + lnbuf[256 + (slot + r) * 2 + 1];
        rs[r] = 1.0 / sqrt(var * (1.0 / 128.0) + 1e-5);
      }
#pragma unroll
      for (int nt = 0; nt < NTL; nt++)
#pragma unroll
        for (int r = 0; r < 4; r++)
          acc2[nt][r] = (float)(((double)acc2[nt][r] - mean[r]) * rs[r]) * gc[nt] + bec[nt];
    } else {
      double sum[4] = {0.0, 0.0, 0.0, 0.0};
#pragma unroll
      for (int nt = 0; nt < NTL; nt++)
#pragma unroll
        for (int r = 0; r < 4; r++) {
          acc2[nt][r] = combine3(acc2[nt][r], acc2x[nt][r], acc2y[nt][r], b2c[nt]);
          sum[r] += (double)acc2[nt][r];
        }
#pragma unroll
      for (int r = 0; r < 4; r++) {
#pragma unroll
        for (int m = 1; m < 16; m <<= 1) sum[r] += __shfl_xor(sum[r], m);
        sum[r] *= (1.0 / 128.0);
      }
      double vs[4] = {0.0, 0.0, 0.0, 0.0};
#pragma unroll
      for (int nt = 0; nt < NTL; nt++)
#pragma unroll
        for (int r = 0; r < 4; r++) {
          double d = (double)acc2[nt][r] - sum[r];
          vs[r] += d * d;
        }
#pragma unroll
      for (int r = 0; r < 4; r++) {
#pragma unroll
        for (int m = 1; m < 16; m <<= 1) vs[r] += __shfl_xor(vs[r], m);
        vs[r] = 1.0 / sqrt(vs[r] * (1.0 / 128.0) + 1e-5);
      }
#pragma unroll
      for (int nt = 0; nt < NTL; nt++)
#pragma unroll
        for (int r = 0; r < 4; r++)
          acc2[nt][r] = (float)(((double)acc2[nt][r] - sum[r]) * vs[r]) * gc[nt] + bec[nt];
    }

    // MODE 2: order all ef reads (layer 1) before variant-1's in-place ef
    // writes below — WAR hazard protection within the block.
    if constexpr (MODE == 2) __syncthreads();

    // ---------------- writeback ----------------
#pragma unroll
    for (int r = 0; r < 4; r++) {
      int idx = r0 + w4 * 16 + (lg << 2) + r;
      if (idx >= p.nrows) continue;
      if constexpr (MODE == 0) {
        float* xr = p.xf + (size_t)idx * 128;
        unsigned short* xh_ = p.xhi_out + (size_t)idx * 128;
        unsigned short* xl_ = p.xlo_out + (size_t)idx * 128;
#pragma unroll
        for (int nt = 0; nt < NTL; nt++) {
          int c = (cb + nt) * 16 + l15; float v = acc2[nt][r];
          xr[c] = v;
          unsigned short hi = f2h(v);
          xh_[c] = hi; xl_[c] = loPart(v, hi);
        }
      } else if constexpr (MODE == 1) {
        float* er = p.ef + (size_t)idx * 128;
#pragma unroll
        for (int nt = 0; nt < NTL; nt++) er[(cb + nt) * 16 + l15] = acc2[nt][r];
      } else if constexpr (MODE == 3) {
        float* xr = p.xf + (size_t)idx * 128;
        unsigned short* xh_ = p.xhi_out + (size_t)idx * 128;
        unsigned short* xl_ = p.xlo_out + (size_t)idx * 128;
#pragma unroll
        for (int nt = 0; nt < NTL; nt++) {
          int c = (cb + nt) * 16 + l15;
          float v = acc2[nt][r] + xr[c];   // residual from f32 master
          xr[c] = v;
          unsigned short hi = f2h(v);
          xh_[c] = hi; xl_[c] = loPart(v, hi);
        }
      } else {  // MODE 2: variant 0 scatters msg (int32 2^22, deterministic);
                //          variant 1 updates eh in place
        if (vrt == 0) {
          int tgt = p.coli[idx];
          int* ar = p.aggi + (size_t)tgt * 128;
#pragma unroll
          for (int nt = 0; nt < NTL; nt++) {
            int q = __double2int_rn((double)acc2[nt][r] * AGG_SCALE_D);
            atomicAdd(&ar[(cb + nt) * 16 + l15], q);
          }
        } else {
          float* er = p.ef + (size_t)idx * 128;
#pragma unroll
          for (int nt = 0; nt < NTL; nt++) {
            int c = (cb + nt) * 16 + l15;
            er[c] = acc2[nt][r] + er[c];
          }
        }
      }
    }
  } else {
    // ---------------- decoder tail: out = h1 @ w2f + b2 (OUT=3, f64 acc) -----
    __syncthreads();   // tail reads h1 rows written by other waves
    if (tid < 192) {
      int row = tid / 3, oc = tid - row * 3;
      int n = r0 + row;
      if (n < p.nrows) {
        double s = (double)w2s[384 + oc];
        for (int k = 0; k < 128; k++) {
          int off = swz(row, k);
          double h = (double)h2f(HI(0)[off]) + (double)h2f(LO(0)[off]) * LO_INV_D;
          s += h * (double)w2s[k * 3 + oc];
        }
        p.out[(size_t)n * 3 + oc] = (float)s;
      }
    }
  }
}

extern "C" void kernel_launch(void* const* d_in, const int* in_sizes, int n_in,
                              void* d_out, int out_size, void* d_ws, size_t ws_size,
                              hipStream_t stream) {
  if (n_in < 31) return;
  const int N = in_sizes[0] / 15;
  const int E = in_sizes[1] / 7;
  const float* x        = (const float*)d_in[0];
  const float* ein      = (const float*)d_in[1];
  const int*   eidx     = (const int*)d_in[2];
  const float* enc_n_w1 = (const float*)d_in[3];
  const float* enc_n_b1 = (const float*)d_in[4];
  const float* enc_n_w2 = (const float*)d_in[5];
  const float* enc_n_b2 = (const float*)d_in[6];
  const float* enc_n_g  = (const float*)d_in[7];
  const float* enc_n_be = (const float*)d_in[8];
  const float* enc_e_w1 = (const float*)d_in[9];
  const float* enc_e_b1 = (const float*)d_in[10];
  const float* enc_e_w2 = (const float*)d_in[11];
  const float* enc_e_b2 = (const float*)d_in[12];
  const float* enc_e_g  = (const float*)d_in[13];
  const float* enc_e_be = (const float*)d_in[14];
  const float* pe_w1    = (const float*)d_in[15];
  const float* pe_b1    = (const float*)d_in[16];
  const float* pe_w2    = (const float*)d_in[17];
  const float* pe_b2    = (const float*)d_in[18];
  const float* pe_g     = (const float*)d_in[19];
  const float* pe_be    = (const float*)d_in[20];
  const float* pn_w1    = (const float*)d_in[21];
  const float* pn_b1    = (const float*)d_in[22];
  const float* pn_w2    = (const float*)d_in[23];
  const float* pn_b2    = (const float*)d_in[24];
  const float* pn_g     = (const float*)d_in[25];
  const float* pn_be    = (const float*)d_in[26];
  const float* dec_w1   = (const float*)d_in[27];
  const float* dec_b1   = (const float*)d_in[28];
  const float* dec_w2   = (const float*)d_in[29];
  const float* dec_b2   = (const float*)d_in[30];

  char* ws = (char*)d_ws;
  size_t off = 0;
  auto carve = [&](size_t bytes) -> void* {
    void* pp = ws + off; off += (bytes + 255) & ~(size_t)255; return pp;
  };
  float* xh            = (float*)carve((size_t)N * 128 * 4);
  unsigned short* xhi  = (unsigned short*)carve((size_t)N * 128 * 2);
  unsigned short* xlo  = (unsigned short*)carve((size_t)N * 128 * 2);
  float* eh            = (float*)carve((size_t)E * 128 * 4);
  int* aggi            = (int*)carve((size_t)N * 128 * 4);

  const int ktab[17] = {15, 128, 7, 128, 384, 384, 384, 128, 128, 128,
                        256, 256, 256, 128, 128, 128, 128};
  unsigned short* pk[17];
  for (int i = 0; i < 17; i++) {
    int kt = (ktab[i] + 31) / 32;
    pk[i] = (unsigned short*)carve((size_t)2 * kt * 8 * 512 * 2);  // hi+lo
  }
  if (off > ws_size) return;  // workspace too small -> fail validation loudly

  RepackParams rp;
  const float* wsrc[17] = {enc_n_w1, enc_n_w2, enc_e_w1, enc_e_w2,
                           pe_w1, pe_w1 + 384 * 128, pe_w1 + 2 * 384 * 128,
                           pe_w2, pe_w2 + 128 * 128, pe_w2 + 2 * 128 * 128,
                           pn_w1, pn_w1 + 256 * 128, pn_w1 + 2 * 256 * 128,
                           pn_w2, pn_w2 + 128 * 128, pn_w2 + 2 * 128 * 128,
                           dec_w1};
  for (int i = 0; i < 17; i++) {
    rp.it[i].src = wsrc[i]; rp.it[i].dst = pk[i];
    rp.it[i].K = ktab[i]; rp.it[i].Kt = (ktab[i] + 31) / 32;
  }
  repack_kernel<<<dim3(96, 17), 256, 0, stream>>>(rp);

  auto wlo = [&](int i) { return pk[i] + (size_t)((ktab[i] + 31) / 32) * 8 * 512; };
  const int gN = (N + 63) / 64, gE = (E + 63) / 64;

  {  // node encoder
    KParams kp{};
    kp.w1h = pk[0]; kp.w1l = wlo(0); kp.w2h = pk[1]; kp.w2l = wlo(1);
    kp.b1 = enc_n_b1; kp.b2 = enc_n_b2; kp.g = enc_n_g; kp.be = enc_n_be;
    kp.srcA = x; kp.xf = xh; kp.xhi_out = xhi; kp.xlo_out = xlo;
    kp.nrows = N; kp.kin = 15;
    gnn_kernel<0><<<gN, 256, 0, stream>>>(kp);
  }
  {  // edge encoder
    KParams kp{};
    kp.w1h = pk[2]; kp.w1l = wlo(2); kp.w2h = pk[3]; kp.w2l = wlo(3);
    kp.b1 = enc_e_b1; kp.b2 = enc_e_b2; kp.g = enc_e_g; kp.be = enc_e_be;
    kp.srcA = ein; kp.ef = eh; kp.nrows = E; kp.kin = 7;
    gnn_kernel<1><<<gE, 256, 0, stream>>>(kp);
  }
  for (int i = 0; i < 3; i++) {
    hipMemsetAsync(aggi, 0, (size_t)N * 128 * 4, stream);
    {  // edge processor (1024 threads: 2 variants x 4 bands x 2 col-halves)
      KParams kp{};
      kp.w1h = pk[4 + i]; kp.w1l = wlo(4 + i);
      kp.w2h = pk[7 + i]; kp.w2l = wlo(7 + i);
      kp.b1 = pe_b1 + i * 128; kp.b2 = pe_b2 + i * 128;
      kp.g = pe_g + i * 128; kp.be = pe_be + i * 128;
      kp.xhi = xhi; kp.xlo = xlo; kp.ef = eh;
      kp.rowi = eidx; kp.coli = eidx + E;
      kp.aggi = aggi; kp.nrows = E;
      gnn_kernel<2><<<gE, 1024, 0, stream>>>(kp);
    }
    {  // node processor (reads deterministic int32 aggregate via double)
      KParams kp{};
      kp.w1h = pk[10 + i]; kp.w1l = wlo(10 + i);
      kp.w2h = pk[13 + i]; kp.w2l = wlo(13 + i);
      kp.b1 = pn_b1 + i * 128; kp.b2 = pn_b2 + i * 128;
      kp.g = pn_g + i * 128; kp.be = pn_be + i * 128;
      kp.aggi = aggi; kp.xhi = xhi; kp.xlo = xlo;
      kp.xf = xh; kp.xhi_out = xhi; kp.xlo_out = xlo; kp.nrows = N;
      gnn_kernel<3><<<gN, 256, 0, stream>>>(kp);
    }
  }
  {  // decoder
    KParams kp{};
    kp.w1h = pk[16]; kp.w1l = wlo(16); kp.b1 = dec_b1;
    kp.xhi = xhi; kp.xlo = xlo; kp.w2f = dec_w2; kp.b2f = dec_b2;
    kp.out = (float*)d_out; kp.nrows = N;
    gnn_kernel<4><<<gN, 256, 0, stream>>>(kp);
  }
}

// Round 19
// 2048.065 us; speedup vs baseline: 1.0588x; 1.0588x over previous
//
#include <hip/hip_runtime.h>
#include <stdint.h>
#include <math.h>

#define DEVI __device__ __forceinline__

typedef __attribute__((ext_vector_type(8))) _Float16 f16x8;
typedef __attribute__((ext_vector_type(4))) float f32x4;

#define LO_SCALE 2048.0f
#define LO_INV (1.0f / 2048.0f)
#define LO_INV_D (1.0 / 2048.0)
// int32 fixed-point aggregation at 2^22, quantized/read back through double:
// per-message error <= 1.2e-7 absolute; integer sum is order-exact.
#define AGG_SCALE_D 4194304.0
#define AGG_INV_D (1.0 / 4194304.0)

DEVI unsigned short f2h(float f) {
  union { _Float16 h; unsigned short u; } v; v.h = (_Float16)f; return v.u;
}
DEVI float h2f(unsigned short u) {
  union { unsigned short u; _Float16 h; } v; v.u = u; return (float)v.h;
}
DEVI unsigned short loPart(float v, unsigned short hi) {
  return f2h((v - h2f(hi)) * LO_SCALE);
}
DEVI f32x4 mfma16(f16x8 a, f16x8 b, f32x4 c) {
  return __builtin_amdgcn_mfma_f32_16x16x32_f16(a, b, c, 0, 0, 0);
}
// Full 4-term pair product: acc += Ah*Bh ; accx += Ah*Bl + Al*Bh ; accy += Al*Bl
// (accx scaled x2048, accy x2048^2). Combine in f64: ~f32-exact GEMM.
DEVI void mfma4(f16x8 ah, f16x8 al, f16x8 bh, f16x8 bl,
                f32x4& acc, f32x4& accx, f32x4& accy) {
  acc  = mfma16(ah, bh, acc);
  accx = mfma16(ah, bl, accx);
  accx = mfma16(al, bh, accx);
  accy = mfma16(al, bl, accy);
}
DEVI float combine3(float a, float ax, float ay, float b) {
  return (float)((double)a + ((double)ax + (double)ay * LO_INV_D) * LO_INV_D + (double)b);
}
// swizzled element offset inside one [rows][128] fp16 tile (row stride 256B).
DEVI int swz(int row, int col) { return row * 128 + (col ^ ((row & 7) << 3)); }

struct KParams {
  const unsigned short* w1h; const unsigned short* w1l;
  const unsigned short* w2h; const unsigned short* w2l;
  const float* b1; const float* b2; const float* g; const float* be;
  const float* srcA;                 // ENC: x/e
  const unsigned short* xhi;         // fp16 hi mirror of xh
  const unsigned short* xlo;         // fp16 lo mirror (x2048)
  float* xf;                         // xh f32 master
  float* ef;                         // eh f32 master
  unsigned short* xhi_out; unsigned short* xlo_out;
  const int* rowi; const int* coli;
  int* aggi;                         // [N,128] int32 2^22 fixed-point aggregate
  float* out;
  const float* w2f; const float* b2f;  // decoder layer-2 (f32)
  int nrows; int kin;
};

struct RepackItem { const float* src; unsigned short* dst; int K; int Kt; };
struct RepackParams { RepackItem it[17]; };

// Pack W [K][128] f32 -> fp16 hi/lo MFMA B-fragments. hi at [0, Kt*8*512),
// lo (x2048) at [Kt*8*512, 2*Kt*8*512).
__global__ __launch_bounds__(256) void repack_kernel(RepackParams rp) {
  const RepackItem w = rp.it[blockIdx.y];
  const int f = blockIdx.x;
  if (f >= w.Kt * 8) return;
  const int kt = f >> 3, nt = f & 7;
  const size_t loOff = (size_t)w.Kt * 8 * 512;
  for (int s = threadIdx.x; s < 512; s += 256) {
    int ln = s >> 3, j = s & 7;
    int k = kt * 32 + ((ln >> 4) << 3) + j;
    int c = nt * 16 + (ln & 15);
    float v = (k < w.K) ? w.src[(size_t)k * 128 + c] : 0.f;
    unsigned short hi = f2h(v);
    w.dst[(size_t)f * 512 + s] = hi;
    w.dst[loOff + (size_t)f * 512 + s] = loPart(v, hi);
  }
}

// Modes: 0=node-encoder 1=edge-encoder 2=edge-processor 3=node-processor 4=decoder
// MODE 2 (col-split, 512 threads / 32 edges / 2 blocks per CU): 8 waves;
// wave -> (vrt = wave>>2, band = (wave>>1)&1, ntg = wave&1). Each wave:
// 16 rows x 64 cols -> 12 f32x4 accumulators (48 VGPR; launch_bounds(512,4)
// caps at 128, no spill). LDS = h1 32KB + wbuf 32KB + lnbuf 2KB = 66KB ->
// 2 independent blocks/CU = 4 waves/SIMD; one block computes while the other
// waits at its staging barrier. Same math/bits as R18 (absmax 0.0078125).
template <int MODE>
__global__ __launch_bounds__((MODE == 2) ? 512 : 256, (MODE == 2) ? 4 : 2)
void gnn_kernel(KParams p) {
  constexpr int NT = (MODE == 2) ? 512 : 256;
  constexpr int REG = (MODE == 2) ? 4096 : 8192;   // elems per hi (or lo) region
  constexpr int NREG = (MODE == 2 || MODE == 3) ? 2 : 1;
  constexpr int NTL = (MODE == 2) ? 4 : 8;         // output col-blocks per wave
  __shared__ __align__(16) unsigned short stA[NREG * 2 * REG];
  __shared__ __align__(16) unsigned short wbuf[(MODE == 2) ? 16384 : 1];  // 2 x 16KB
  __shared__ double lnbuf[(MODE == 2) ? 256 : 1];
  __shared__ float w2s[(MODE == 4) ? 392 : 1];

  const int tid = threadIdx.x;
  const int lane = tid & 63;
  const int wave = tid >> 6;
  const int w4 = (MODE == 2) ? ((wave >> 1) & 1) : wave;  // 16-row band index
  const int vrt = (MODE == 2) ? (wave >> 2) : 0;   // variant: 0=msg 1=edge-update
  const int ntg = (MODE == 2) ? (wave & 1) : 0;    // col half
  const int cb = ntg * 4;                          // col-block base (nt units)
  const int r0 = blockIdx.x * ((MODE == 2) ? 32 : 64);
  const int l15 = lane & 15;
  const int lg = lane >> 4;

  auto HI = [&](int t) { return stA + 2 * t * REG; };
  auto LO = [&](int t) { return stA + 2 * t * REG + REG; };

  // stage one 16KB weight step (4096 hi + 4096 lo elems) into wbuf[buf]
  auto stageW = [&](int s, int buf) {
    const unsigned short* h = (s < 12) ? p.w1h + s * 4096 : p.w2h + (s - 12) * 4096;
    const unsigned short* l = (s < 12) ? p.w1l + s * 4096 : p.w2l + (s - 12) * 4096;
    for (int i = tid; i < 1024; i += NT) {
      *(f16x8*)&wbuf[buf * 8192 + i * 8] =
          *(const f16x8*)((i < 512) ? h + i * 8 : l + (i - 512) * 8);
    }
  };

  // ---------------- stage inputs (fp16 hi/lo, swizzled) — not MODE 2 ----------
  if constexpr (MODE == 3) {
    for (int s = tid; s < 1024; s += NT) {
      int row = s >> 4, cc = (s & 15) * 8;
      int n = r0 + row;
      int off = swz(row, cc);
      if (n < p.nrows) {
        const int* ap = p.aggi + (size_t)n * 128 + cc;
        union { unsigned short u[8]; f16x8 v; } th, tl;
#pragma unroll
        for (int j = 0; j < 8; j++) {
          float v = (float)((double)ap[j] * AGG_INV_D);   // exact int->double->f32
          th.u[j] = f2h(v); tl.u[j] = loPart(v, th.u[j]);
        }
        *(f16x8*)&HI(0)[off] = th.v; *(f16x8*)&LO(0)[off] = tl.v;
        *(f16x8*)&HI(1)[off] = *(const f16x8*)(p.xhi + (size_t)n * 128 + cc);
        *(f16x8*)&LO(1)[off] = *(const f16x8*)(p.xlo + (size_t)n * 128 + cc);
      } else {
        f16x8 z = {0,0,0,0,0,0,0,0};
        *(f16x8*)&HI(0)[off] = z; *(f16x8*)&LO(0)[off] = z;
        *(f16x8*)&HI(1)[off] = z; *(f16x8*)&LO(1)[off] = z;
      }
    }
  } else if constexpr (MODE == 0 || MODE == 1) {
    for (int s = tid; s < 256; s += NT) {
      int row = s >> 2, cc = (s & 3) * 8;
      int n = r0 + row;
      union { unsigned short u[8]; f16x8 v; } th, tl;
#pragma unroll
      for (int j = 0; j < 8; j++) {
        int k = cc + j;
        float v = (n < p.nrows && k < p.kin) ? p.srcA[(size_t)n * p.kin + k] : 0.f;
        th.u[j] = f2h(v); tl.u[j] = loPart(v, th.u[j]);
      }
      int off = swz(row, cc);
      *(f16x8*)&HI(0)[off] = th.v; *(f16x8*)&LO(0)[off] = tl.v;
    }
  } else if constexpr (MODE == 4) {
    for (int s = tid; s < 1024; s += NT) {
      int row = s >> 4, cc = (s & 15) * 8;
      int n = r0 + row;
      int off = swz(row, cc);
      f16x8 z = {0,0,0,0,0,0,0,0};
      if (n < p.nrows) {
        *(f16x8*)&HI(0)[off] = *(const f16x8*)(p.xhi + (size_t)n * 128 + cc);
        *(f16x8*)&LO(0)[off] = *(const f16x8*)(p.xlo + (size_t)n * 128 + cc);
      } else { *(f16x8*)&HI(0)[off] = z; *(f16x8*)&LO(0)[off] = z; }
    }
    for (int s = tid; s < 387; s += NT) w2s[s] = (s < 384) ? p.w2f[s] : p.b2f[s - 384];
  } else {  // MODE 2: weight prologue only
    stageW(0, 0);
  }
  __syncthreads();

  // ---------------- layer 1 (K = K1T*32) ----------------
  constexpr int K1T = (MODE == 2) ? 12 : (MODE == 3) ? 8 : (MODE == 4) ? 4 : 1;
  const f32x4 zz = {0.f, 0.f, 0.f, 0.f};
  f32x4 acc1[NTL], acc1x[NTL], acc1y[NTL];
#pragma unroll
  for (int nt = 0; nt < NTL; nt++) { acc1[nt] = zz; acc1x[nt] = zz; acc1y[nt] = zz; }
  const int arow = w4 * 16 + l15;
  const int acol = lg << 3;

  if constexpr (MODE == 2) {
    // Per-lane direct-from-global A operands. Lane's A row = edge r0+arow.
    const int ridx = r0 + arow;
    const int ec = (ridx < p.nrows) ? ridx : 0;   // clamped (outputs discarded)
    const int nc = p.coli[ec], nr = p.rowi[ec];
    // msg variant: [Xc, Xr, Ee] ; edge-update variant: [Xr, Xc, Ee]
    const unsigned short* aH = p.xhi + (size_t)(vrt ? nr : nc) * 128;
    const unsigned short* aL = p.xlo + (size_t)(vrt ? nr : nc) * 128;
    const unsigned short* bH = p.xhi + (size_t)(vrt ? nc : nr) * 128;
    const unsigned short* bL = p.xlo + (size_t)(vrt ? nc : nr) * 128;
    const float* ep = p.ef + (size_t)ec * 128;
#pragma unroll
    for (int kt = 0; kt < 12; kt++) {
      const int cur = kt & 1;
      stageW(kt + 1, cur ^ 1);   // W1[kt+1] or (kt=11) W2[0]
      const int kc = (kt & 3) * 32 + acol;
      f16x8 ah, al;
      if (kt < 4)      { ah = *(const f16x8*)(aH + kc); al = *(const f16x8*)(aL + kc); }
      else if (kt < 8) { ah = *(const f16x8*)(bH + kc); al = *(const f16x8*)(bL + kc); }
      else {
        union { unsigned short u[8]; f16x8 v; } th, tl;
#pragma unroll
        for (int j = 0; j < 8; j++) {
          float v = ep[kc + j];
          th.u[j] = f2h(v); tl.u[j] = loPart(v, th.u[j]);
        }
        ah = th.v; al = tl.v;
      }
#pragma unroll
      for (int nt = 0; nt < NTL; nt++) {
        f16x8 bh = *(const f16x8*)&wbuf[cur * 8192 + (cb + nt) * 512 + lane * 8];
        f16x8 bl = *(const f16x8*)&wbuf[cur * 8192 + 4096 + (cb + nt) * 512 + lane * 8];
        mfma4(ah, al, bh, bl, acc1[nt], acc1x[nt], acc1y[nt]);
      }
      __syncthreads();
    }
  } else {
#pragma unroll
    for (int kt = 0; kt < K1T; kt++) {
      int t = kt >> 2;
      int so = swz(arow, (kt & 3) * 32 + acol);
      f16x8 ah = *(const f16x8*)&HI(t)[so];
      f16x8 al = *(const f16x8*)&LO(t)[so];
#pragma unroll
      for (int nt = 0; nt < NTL; nt++) {
        f16x8 bh = *(const f16x8*)&p.w1h[(size_t)(kt * 8 + nt) * 512 + lane * 8];
        f16x8 bl = *(const f16x8*)&p.w1l[(size_t)(kt * 8 + nt) * 512 + lane * 8];
        mfma4(ah, al, bh, bl, acc1[nt], acc1x[nt], acc1y[nt]);
      }
    }
  }

  // ---------------- h1 = relu(acc + b1) -> LDS hi/lo (region vrt) ----------
  float b1c[NTL];
#pragma unroll
  for (int nt = 0; nt < NTL; nt++) b1c[nt] = p.b1[(cb + nt) * 16 + l15];
#pragma unroll
  for (int nt = 0; nt < NTL; nt++) {
#pragma unroll
    for (int r = 0; r < 4; r++) {
      int row = w4 * 16 + (lg << 2) + r;
      int col = (cb + nt) * 16 + l15;
      int off = swz(row, col);
      float v = combine3(acc1[nt][r], acc1x[nt][r], acc1y[nt][r], b1c[nt]);
      v = v > 0.f ? v : 0.f;
      unsigned short hi = f2h(v);
      HI(vrt)[off] = hi; LO(vrt)[off] = loPart(v, hi);
    }
  }
  // MODE 2: layer-2 reads h1 cols written by the sibling ntg wave -> barrier.
  if constexpr (MODE == 2) __syncthreads();

  if constexpr (MODE != 4) {
    // ---------------- layer 2 (K=128 from h1 in LDS region vrt) ----------------
    f32x4 acc2[NTL], acc2x[NTL], acc2y[NTL];
#pragma unroll
    for (int nt = 0; nt < NTL; nt++) { acc2[nt] = zz; acc2x[nt] = zz; acc2y[nt] = zz; }
#pragma unroll
    for (int kt = 0; kt < 4; kt++) {
      if constexpr (MODE == 2) {
        const int cur = (12 + kt) & 1;
        if (kt < 3) stageW(13 + kt, cur ^ 1);   // W2[kt+1] (steps 13,14,15)
        int so = swz(arow, kt * 32 + acol);
        f16x8 ah = *(const f16x8*)&HI(vrt)[so];
        f16x8 al = *(const f16x8*)&LO(vrt)[so];
#pragma unroll
        for (int nt = 0; nt < NTL; nt++) {
          f16x8 bh = *(const f16x8*)&wbuf[cur * 8192 + (cb + nt) * 512 + lane * 8];
          f16x8 bl = *(const f16x8*)&wbuf[cur * 8192 + 4096 + (cb + nt) * 512 + lane * 8];
          mfma4(ah, al, bh, bl, acc2[nt], acc2x[nt], acc2y[nt]);
        }
        if (kt < 3) __syncthreads();
      } else {
        int so = swz(arow, kt * 32 + acol);
        f16x8 ah = *(const f16x8*)&HI(vrt)[so];
        f16x8 al = *(const f16x8*)&LO(vrt)[so];
#pragma unroll
        for (int nt = 0; nt < NTL; nt++) {
          f16x8 bh = *(const f16x8*)&p.w2h[(size_t)(kt * 8 + nt) * 512 + lane * 8];
          f16x8 bl = *(const f16x8*)&p.w2l[(size_t)(kt * 8 + nt) * 512 + lane * 8];
          mfma4(ah, al, bh, bl, acc2[nt], acc2x[nt], acc2y[nt]);
        }
      }
    }

    // ---------------- LayerNorm epilogue (f64 statistics) ----------------
    float b2c[NTL], gc[NTL], bec[NTL];
#pragma unroll
    for (int nt = 0; nt < NTL; nt++) {
      int c = (cb + nt) * 16 + l15;
      b2c[nt] = p.b2[c]; gc[nt] = p.g[c]; bec[nt] = p.be[c];
    }
    if constexpr (MODE == 2) {
      // cross-wave LN: each wave holds 64 of the row's 128 cols; exchange f64
      // partials through LDS; combine in fixed (ntg0 + ntg1) order.
      const int slot = ((vrt * 2 + w4) * 4 + lg) * 4;   // + r -> 0..63
      double ps[4] = {0.0, 0.0, 0.0, 0.0};
#pragma unroll
      for (int nt = 0; nt < NTL; nt++)
#pragma unroll
        for (int r = 0; r < 4; r++) {
          acc2[nt][r] = combine3(acc2[nt][r], acc2x[nt][r], acc2y[nt][r], b2c[nt]);
          ps[r] += (double)acc2[nt][r];
        }
#pragma unroll
      for (int r = 0; r < 4; r++)
#pragma unroll
        for (int m = 1; m < 16; m <<= 1) ps[r] += __shfl_xor(ps[r], m);
      if (l15 == 0) {
#pragma unroll
        for (int r = 0; r < 4; r++) lnbuf[(slot + r) * 2 + ntg] = ps[r];
      }
      __syncthreads();
      double mean[4];
#pragma unroll
      for (int r = 0; r < 4; r++)
        mean[r] = (lnbuf[(slot + r) * 2] + lnbuf[(slot + r) * 2 + 1]) * (1.0 / 128.0);
      double pv[4] = {0.0, 0.0, 0.0, 0.0};
#pragma unroll
      for (int nt = 0; nt < NTL; nt++)
#pragma unroll
        for (int r = 0; r < 4; r++) {
          double d = (double)acc2[nt][r] - mean[r];
          pv[r] += d * d;
        }
#pragma unroll
      for (int r = 0; r < 4; r++)
#pragma unroll
        for (int m = 1; m < 16; m <<= 1) pv[r] += __shfl_xor(pv[r], m);
      if (l15 == 0) {
#pragma unroll
        for (int r = 0; r < 4; r++) lnbuf[128 + (slot + r) * 2 + ntg] = pv[r];
      }
      __syncthreads();
      double rs[4];
#pragma unroll
      for (int r = 0; r < 4; r++) {
        double var = lnbuf[128 + (slot + r) * 2] + lnbuf[128 + (slot + r) * 2 + 1];
        rs[r] = 1.0 / sqrt(var * (1.0 / 128.0) + 1e-5);
      }
#pragma unroll
      for (int nt = 0; nt < NTL; nt++)
#pragma unroll
        for (int r = 0; r < 4; r++)
          acc2[nt][r] = (float)(((double)acc2[nt][r] - mean[r]) * rs[r]) * gc[nt] + bec[nt];
    } else {
      double sum[4] = {0.0, 0.0, 0.0, 0.0};
#pragma unroll
      for (int nt = 0; nt < NTL; nt++)
#pragma unroll
        for (int r = 0; r < 4; r++) {
          acc2[nt][r] = combine3(acc2[nt][r], acc2x[nt][r], acc2y[nt][r], b2c[nt]);
          sum[r] += (double)acc2[nt][r];
        }
#pragma unroll
      for (int r = 0; r < 4; r++) {
#pragma unroll
        for (int m = 1; m < 16; m <<= 1) sum[r] += __shfl_xor(sum[r], m);
        sum[r] *= (1.0 / 128.0);
      }
      double vs[4] = {0.0, 0.0, 0.0, 0.0};
#pragma unroll
      for (int nt = 0; nt < NTL; nt++)
#pragma unroll
        for (int r = 0; r < 4; r++) {
          double d = (double)acc2[nt][r] - sum[r];
          vs[r] += d * d;
        }
#pragma unroll
      for (int r = 0; r < 4; r++) {
#pragma unroll
        for (int m = 1; m < 16; m <<= 1) vs[r] += __shfl_xor(vs[r], m);
        vs[r] = 1.0 / sqrt(vs[r] * (1.0 / 128.0) + 1e-5);
      }
#pragma unroll
      for (int nt = 0; nt < NTL; nt++)
#pragma unroll
        for (int r = 0; r < 4; r++)
          acc2[nt][r] = (float)(((double)acc2[nt][r] - sum[r]) * vs[r]) * gc[nt] + bec[nt];
    }

    // MODE 2: order all ef reads (layer 1) before variant-1's in-place ef
    // writes below — WAR hazard protection within the block.
    if constexpr (MODE == 2) __syncthreads();

    // ---------------- writeback ----------------
#pragma unroll
    for (int r = 0; r < 4; r++) {
      int idx = r0 + w4 * 16 + (lg << 2) + r;
      if (idx >= p.nrows) continue;
      if constexpr (MODE == 0) {
        float* xr = p.xf + (size_t)idx * 128;
        unsigned short* xh_ = p.xhi_out + (size_t)idx * 128;
        unsigned short* xl_ = p.xlo_out + (size_t)idx * 128;
#pragma unroll
        for (int nt = 0; nt < NTL; nt++) {
          int c = (cb + nt) * 16 + l15; float v = acc2[nt][r];
          xr[c] = v;
          unsigned short hi = f2h(v);
          xh_[c] = hi; xl_[c] = loPart(v, hi);
        }
      } else if constexpr (MODE == 1) {
        float* er = p.ef + (size_t)idx * 128;
#pragma unroll
        for (int nt = 0; nt < NTL; nt++) er[(cb + nt) * 16 + l15] = acc2[nt][r];
      } else if constexpr (MODE == 3) {
        float* xr = p.xf + (size_t)idx * 128;
        unsigned short* xh_ = p.xhi_out + (size_t)idx * 128;
        unsigned short* xl_ = p.xlo_out + (size_t)idx * 128;
#pragma unroll
        for (int nt = 0; nt < NTL; nt++) {
          int c = (cb + nt) * 16 + l15;
          float v = acc2[nt][r] + xr[c];   // residual from f32 master
          xr[c] = v;
          unsigned short hi = f2h(v);
          xh_[c] = hi; xl_[c] = loPart(v, hi);
        }
      } else {  // MODE 2: variant 0 scatters msg (int32 2^22, deterministic);
                //          variant 1 updates eh in place
        if (vrt == 0) {
          int tgt = p.coli[idx];
          int* ar = p.aggi + (size_t)tgt * 128;
#pragma unroll
          for (int nt = 0; nt < NTL; nt++) {
            int q = __double2int_rn((double)acc2[nt][r] * AGG_SCALE_D);
            atomicAdd(&ar[(cb + nt) * 16 + l15], q);
          }
        } else {
          float* er = p.ef + (size_t)idx * 128;
#pragma unroll
          for (int nt = 0; nt < NTL; nt++) {
            int c = (cb + nt) * 16 + l15;
            er[c] = acc2[nt][r] + er[c];
          }
        }
      }
    }
  } else {
    // ---------------- decoder tail: out = h1 @ w2f + b2 (OUT=3, f64 acc) -----
    __syncthreads();   // tail reads h1 rows written by other waves
    if (tid < 192) {
      int row = tid / 3, oc = tid - row * 3;
      int n = r0 + row;
      if (n < p.nrows) {
        double s = (double)w2s[384 + oc];
        for (int k = 0; k < 128; k++) {
          int off = swz(row, k);
          double h = (double)h2f(HI(0)[off]) + (double)h2f(LO(0)[off]) * LO_INV_D;
          s += h * (double)w2s[k * 3 + oc];
        }
        p.out[(size_t)n * 3 + oc] = (float)s;
      }
    }
  }
}

extern "C" void kernel_launch(void* const* d_in, const int* in_sizes, int n_in,
                              void* d_out, int out_size, void* d_ws, size_t ws_size,
                              hipStream_t stream) {
  if (n_in < 31) return;
  const int N = in_sizes[0] / 15;
  const int E = in_sizes[1] / 7;
  const float* x        = (const float*)d_in[0];
  const float* ein      = (const float*)d_in[1];
  const int*   eidx     = (const int*)d_in[2];
  const float* enc_n_w1 = (const float*)d_in[3];
  const float* enc_n_b1 = (const float*)d_in[4];
  const float* enc_n_w2 = (const float*)d_in[5];
  const float* enc_n_b2 = (const float*)d_in[6];
  const float* enc_n_g  = (const float*)d_in[7];
  const float* enc_n_be = (const float*)d_in[8];
  const float* enc_e_w1 = (const float*)d_in[9];
  const float* enc_e_b1 = (const float*)d_in[10];
  const float* enc_e_w2 = (const float*)d_in[11];
  const float* enc_e_b2 = (const float*)d_in[12];
  const float* enc_e_g  = (const float*)d_in[13];
  const float* enc_e_be = (const float*)d_in[14];
  const float* pe_w1    = (const float*)d_in[15];
  const float* pe_b1    = (const float*)d_in[16];
  const float* pe_w2    = (const float*)d_in[17];
  const float* pe_b2    = (const float*)d_in[18];
  const float* pe_g     = (const float*)d_in[19];
  const float* pe_be    = (const float*)d_in[20];
  const float* pn_w1    = (const float*)d_in[21];
  const float* pn_b1    = (const float*)d_in[22];
  const float* pn_w2    = (const float*)d_in[23];
  const float* pn_b2    = (const float*)d_in[24];
  const float* pn_g     = (const float*)d_in[25];
  const float* pn_be    = (const float*)d_in[26];
  const float* dec_w1   = (const float*)d_in[27];
  const float* dec_b1   = (const float*)d_in[28];
  const float* dec_w2   = (const float*)d_in[29];
  const float* dec_b2   = (const float*)d_in[30];

  char* ws = (char*)d_ws;
  size_t off = 0;
  auto carve = [&](size_t bytes) -> void* {
    void* pp = ws + off; off += (bytes + 255) & ~(size_t)255; return pp;
  };
  float* xh            = (float*)carve((size_t)N * 128 * 4);
  unsigned short* xhi  = (unsigned short*)carve((size_t)N * 128 * 2);
  unsigned short* xlo  = (unsigned short*)carve((size_t)N * 128 * 2);
  float* eh            = (float*)carve((size_t)E * 128 * 4);
  int* aggi            = (int*)carve((size_t)N * 128 * 4);

  const int ktab[17] = {15, 128, 7, 128, 384, 384, 384, 128, 128, 128,
                        256, 256, 256, 128, 128, 128, 128};
  unsigned short* pk[17];
  for (int i = 0; i < 17; i++) {
    int kt = (ktab[i] + 31) / 32;
    pk[i] = (unsigned short*)carve((size_t)2 * kt * 8 * 512 * 2);  // hi+lo
  }
  if (off > ws_size) return;  // workspace too small -> fail validation loudly

  RepackParams rp;
  const float* wsrc[17] = {enc_n_w1, enc_n_w2, enc_e_w1, enc_e_w2,
                           pe_w1, pe_w1 + 384 * 128, pe_w1 + 2 * 384 * 128,
                           pe_w2, pe_w2 + 128 * 128, pe_w2 + 2 * 128 * 128,
                           pn_w1, pn_w1 + 256 * 128, pn_w1 + 2 * 256 * 128,
                           pn_w2, pn_w2 + 128 * 128, pn_w2 + 2 * 128 * 128,
                           dec_w1};
  for (int i = 0; i < 17; i++) {
    rp.it[i].src = wsrc[i]; rp.it[i].dst = pk[i];
    rp.it[i].K = ktab[i]; rp.it[i].Kt = (ktab[i] + 31) / 32;
  }
  repack_kernel<<<dim3(96, 17), 256, 0, stream>>>(rp);

  auto wlo = [&](int i) { return pk[i] + (size_t)((ktab[i] + 31) / 32) * 8 * 512; };
  const int gN = (N + 63) / 64, gE = (E + 63) / 64, gE32 = (E + 31) / 32;

  {  // node encoder
    KParams kp{};
    kp.w1h = pk[0]; kp.w1l = wlo(0); kp.w2h = pk[1]; kp.w2l = wlo(1);
    kp.b1 = enc_n_b1; kp.b2 = enc_n_b2; kp.g = enc_n_g; kp.be = enc_n_be;
    kp.srcA = x; kp.xf = xh; kp.xhi_out = xhi; kp.xlo_out = xlo;
    kp.nrows = N; kp.kin = 15;
    gnn_kernel<0><<<gN, 256, 0, stream>>>(kp);
  }
  {  // edge encoder
    KParams kp{};
    kp.w1h = pk[2]; kp.w1l = wlo(2); kp.w2h = pk[3]; kp.w2l = wlo(3);
    kp.b1 = enc_e_b1; kp.b2 = enc_e_b2; kp.g = enc_e_g; kp.be = enc_e_be;
    kp.srcA = ein; kp.ef = eh; kp.nrows = E; kp.kin = 7;
    gnn_kernel<1><<<gE, 256, 0, stream>>>(kp);
  }
  for (int i = 0; i < 3; i++) {
    hipMemsetAsync(aggi, 0, (size_t)N * 128 * 4, stream);
    {  // edge processor (512 threads / 32 edges: 2 variants x 2 bands x 2 col-halves)
      KParams kp{};
      kp.w1h = pk[4 + i]; kp.w1l = wlo(4 + i);
      kp.w2h = pk[7 + i]; kp.w2l = wlo(7 + i);
      kp.b1 = pe_b1 + i * 128; kp.b2 = pe_b2 + i * 128;
      kp.g = pe_g + i * 128; kp.be = pe_be + i * 128;
      kp.xhi = xhi; kp.xlo = xlo; kp.ef = eh;
      kp.rowi = eidx; kp.coli = eidx + E;
      kp.aggi = aggi; kp.nrows = E;
      gnn_kernel<2><<<gE32, 512, 0, stream>>>(kp);
    }
    {  // node processor (reads deterministic int32 aggregate via double)
      KParams kp{};
      kp.w1h = pk[10 + i]; kp.w1l = wlo(10 + i);
      kp.w2h = pk[13 + i]; kp.w2l = wlo(13 + i);
      kp.b1 = pn_b1 + i * 128; kp.b2 = pn_b2 + i * 128;
      kp.g = pn_g + i * 128; kp.be = pn_be + i * 128;
      kp.aggi = aggi; kp.xhi = xhi; kp.xlo = xlo;
      kp.xf = xh; kp.xhi_out = xhi; kp.xlo_out = xlo; kp.nrows = N;
      gnn_kernel<3><<<gN, 256, 0, stream>>>(kp);
    }
  }
  {  // decoder
    KParams kp{};
    kp.w1h = pk[16]; kp.w1l = wlo(16); kp.b1 = dec_b1;
    kp.xhi = xhi; kp.xlo = xlo; kp.w2f = dec_w2; kp.b2f = dec_b2;
    kp.out = (float*)d_out; kp.nrows = N;
    gnn_kernel<4><<<gN, 256, 0, stream>>>(kp);
  }
}

// Round 20
// 1891.454 us; speedup vs baseline: 1.1464x; 1.0828x over previous
//
#include <hip/hip_runtime.h>
#include <stdint.h>
#include <math.h>

#define DEVI __device__ __forceinline__

typedef __attribute__((ext_vector_type(8))) _Float16 f16x8;
typedef __attribute__((ext_vector_type(4))) float f32x4;

#define LO_SCALE 2048.0f
#define LO_INV (1.0f / 2048.0f)
#define LO_INV_D (1.0 / 2048.0)
// int32 fixed-point aggregation at 2^22, quantized/read back through double:
// per-message error <= 1.2e-7 absolute; integer sum is order-exact.
#define AGG_SCALE_D 4194304.0
#define AGG_INV_D (1.0 / 4194304.0)

DEVI unsigned short f2h(float f) {
  union { _Float16 h; unsigned short u; } v; v.h = (_Float16)f; return v.u;
}
DEVI float h2f(unsigned short u) {
  union { unsigned short u; _Float16 h; } v; v.u = u; return (float)v.h;
}
DEVI unsigned short loPart(float v, unsigned short hi) {
  return f2h((v - h2f(hi)) * LO_SCALE);
}
DEVI f32x4 mfma16(f16x8 a, f16x8 b, f32x4 c) {
  return __builtin_amdgcn_mfma_f32_16x16x32_f16(a, b, c, 0, 0, 0);
}
// Full 4-term pair product: acc += Ah*Bh ; accx += Ah*Bl + Al*Bh ; accy += Al*Bl
// (accx scaled x2048, accy x2048^2). Combine in f64: ~f32-exact GEMM.
DEVI void mfma4(f16x8 ah, f16x8 al, f16x8 bh, f16x8 bl,
                f32x4& acc, f32x4& accx, f32x4& accy) {
  acc  = mfma16(ah, bh, acc);
  accx = mfma16(ah, bl, accx);
  accx = mfma16(al, bh, accx);
  accy = mfma16(al, bl, accy);
}
DEVI float combine3(float a, float ax, float ay, float b) {
  return (float)((double)a + ((double)ax + (double)ay * LO_INV_D) * LO_INV_D + (double)b);
}
// swizzled element offset inside one [rows][128] fp16 tile (row stride 256B).
DEVI int swz(int row, int col) { return row * 128 + (col ^ ((row & 7) << 3)); }

struct KParams {
  const unsigned short* w1h; const unsigned short* w1l;
  const unsigned short* w2h; const unsigned short* w2l;
  const float* b1; const float* b2; const float* g; const float* be;
  const float* srcA;                 // ENC: x/e
  const unsigned short* xhi;         // fp16 hi mirror of xh
  const unsigned short* xlo;         // fp16 lo mirror (x2048)
  float* xf;                         // xh f32 master
  float* ef;                         // eh f32 master
  unsigned short* xhi_out; unsigned short* xlo_out;
  const int* rowi; const int* coli;
  int* aggi;                         // [N,128] int32 2^22 fixed-point aggregate
  float* out;
  const float* w2f; const float* b2f;  // decoder layer-2 (f32)
  int nrows; int kin;
};

struct RepackItem { const float* src; unsigned short* dst; int K; int Kt; };
struct RepackParams { RepackItem it[17]; };

// Pack W [K][128] f32 -> fp16 hi/lo MFMA B-fragments. hi at [0, Kt*8*512),
// lo (x2048) at [Kt*8*512, 2*Kt*8*512).
__global__ __launch_bounds__(256) void repack_kernel(RepackParams rp) {
  const RepackItem w = rp.it[blockIdx.y];
  const int f = blockIdx.x;
  if (f >= w.Kt * 8) return;
  const int kt = f >> 3, nt = f & 7;
  const size_t loOff = (size_t)w.Kt * 8 * 512;
  for (int s = threadIdx.x; s < 512; s += 256) {
    int ln = s >> 3, j = s & 7;
    int k = kt * 32 + ((ln >> 4) << 3) + j;
    int c = nt * 16 + (ln & 15);
    float v = (k < w.K) ? w.src[(size_t)k * 128 + c] : 0.f;
    unsigned short hi = f2h(v);
    w.dst[(size_t)f * 512 + s] = hi;
    w.dst[loOff + (size_t)f * 512 + s] = loPart(v, hi);
  }
}

// Modes: 0=node-encoder 1=edge-encoder 2=edge-processor 3=node-processor 4=decoder
// MODE 2 (R16 structure + explicit occupancy bound): 768 threads (12 waves) over
// 96 edges; waves 0-5 = msg variant (bands 0-5), waves 6-11 = edge-update.
// __launch_bounds__(768, 3): LDS (128KB) caps at 1 block/CU = 3 waves/SIMD, so
// min-3-waves costs nothing but raises the VGPR cap to 170 — stops the
// allocator's 6-waves heuristic (84 VGPR) that spilled the 96-reg mfma4
// accumulators to scratch in R16. Math/bits identical to R16 -> absmax
// bit-identical 0.0078125.
template <int MODE>
__global__ __launch_bounds__((MODE == 2) ? 768 : 256, (MODE == 2) ? 3 : 2)
void gnn_kernel(KParams p) {
  constexpr int NT = (MODE == 2) ? 768 : 256;
  constexpr int REG = (MODE == 2) ? 12288 : 8192;  // elems per hi (or lo) region
  constexpr int NREG = (MODE == 2 || MODE == 3) ? 2 : 1;
  __shared__ __align__(16) unsigned short stA[NREG * 2 * REG];
  __shared__ __align__(16) unsigned short wbuf[(MODE == 2) ? 16384 : 1];  // 2 x 16KB
  __shared__ float w2s[(MODE == 4) ? 392 : 1];

  const int tid = threadIdx.x;
  const int lane = tid & 63;
  const int wave = tid >> 6;
  const int w4 = (MODE == 2) ? (wave % 6) : wave;  // 16-row band index
  const int vrt = (MODE == 2) ? (wave / 6) : 0;    // variant: 0=msg 1=edge-update
  const int r0 = blockIdx.x * ((MODE == 2) ? 96 : 64);
  const int l15 = lane & 15;
  const int lg = lane >> 4;

  auto HI = [&](int t) { return stA + 2 * t * REG; };
  auto LO = [&](int t) { return stA + 2 * t * REG + REG; };

  // stage one 16KB weight step (8192 elems: 4096 hi + 4096 lo) into wbuf[buf]
  auto stageW = [&](int s, int buf) {
    const unsigned short* h = (s < 12) ? p.w1h + s * 4096 : p.w2h + (s - 12) * 4096;
    const unsigned short* l = (s < 12) ? p.w1l + s * 4096 : p.w2l + (s - 12) * 4096;
    for (int i = tid; i < 1024; i += NT) {
      *(f16x8*)&wbuf[buf * 8192 + i * 8] =
          *(const f16x8*)((i < 512) ? h + i * 8 : l + (i - 512) * 8);
    }
  };

  // ---------------- stage inputs (fp16 hi/lo, swizzled) — not MODE 2 ----------
  if constexpr (MODE == 3) {
    for (int s = tid; s < 1024; s += NT) {
      int row = s >> 4, cc = (s & 15) * 8;
      int n = r0 + row;
      int off = swz(row, cc);
      if (n < p.nrows) {
        const int* ap = p.aggi + (size_t)n * 128 + cc;
        union { unsigned short u[8]; f16x8 v; } th, tl;
#pragma unroll
        for (int j = 0; j < 8; j++) {
          float v = (float)((double)ap[j] * AGG_INV_D);   // exact int->double->f32
          th.u[j] = f2h(v); tl.u[j] = loPart(v, th.u[j]);
        }
        *(f16x8*)&HI(0)[off] = th.v; *(f16x8*)&LO(0)[off] = tl.v;
        *(f16x8*)&HI(1)[off] = *(const f16x8*)(p.xhi + (size_t)n * 128 + cc);
        *(f16x8*)&LO(1)[off] = *(const f16x8*)(p.xlo + (size_t)n * 128 + cc);
      } else {
        f16x8 z = {0,0,0,0,0,0,0,0};
        *(f16x8*)&HI(0)[off] = z; *(f16x8*)&LO(0)[off] = z;
        *(f16x8*)&HI(1)[off] = z; *(f16x8*)&LO(1)[off] = z;
      }
    }
  } else if constexpr (MODE == 0 || MODE == 1) {
    for (int s = tid; s < 256; s += NT) {
      int row = s >> 2, cc = (s & 3) * 8;
      int n = r0 + row;
      union { unsigned short u[8]; f16x8 v; } th, tl;
#pragma unroll
      for (int j = 0; j < 8; j++) {
        int k = cc + j;
        float v = (n < p.nrows && k < p.kin) ? p.srcA[(size_t)n * p.kin + k] : 0.f;
        th.u[j] = f2h(v); tl.u[j] = loPart(v, th.u[j]);
      }
      int off = swz(row, cc);
      *(f16x8*)&HI(0)[off] = th.v; *(f16x8*)&LO(0)[off] = tl.v;
    }
  } else if constexpr (MODE == 4) {
    for (int s = tid; s < 1024; s += NT) {
      int row = s >> 4, cc = (s & 15) * 8;
      int n = r0 + row;
      int off = swz(row, cc);
      f16x8 z = {0,0,0,0,0,0,0,0};
      if (n < p.nrows) {
        *(f16x8*)&HI(0)[off] = *(const f16x8*)(p.xhi + (size_t)n * 128 + cc);
        *(f16x8*)&LO(0)[off] = *(const f16x8*)(p.xlo + (size_t)n * 128 + cc);
      } else { *(f16x8*)&HI(0)[off] = z; *(f16x8*)&LO(0)[off] = z; }
    }
    for (int s = tid; s < 387; s += NT) w2s[s] = (s < 384) ? p.w2f[s] : p.b2f[s - 384];
  } else {  // MODE 2: weight prologue only
    stageW(0, 0);
  }
  __syncthreads();

  // ---------------- layer 1 (K = K1T*32) ----------------
  constexpr int K1T = (MODE == 2) ? 12 : (MODE == 3) ? 8 : (MODE == 4) ? 4 : 1;
  const f32x4 zz = {0.f, 0.f, 0.f, 0.f};
  f32x4 acc1[8], acc1x[8], acc1y[8];
#pragma unroll
  for (int nt = 0; nt < 8; nt++) { acc1[nt] = zz; acc1x[nt] = zz; acc1y[nt] = zz; }
  const int arow = w4 * 16 + l15;
  const int acol = lg << 3;

  if constexpr (MODE == 2) {
    // Per-lane direct-from-global A operands. Lane's A row = edge r0+arow.
    const int ridx = r0 + arow;
    const int ec = (ridx < p.nrows) ? ridx : 0;   // clamped (outputs discarded)
    const int nc = p.coli[ec], nr = p.rowi[ec];
    // msg variant: [Xc, Xr, Ee] ; edge-update variant: [Xr, Xc, Ee]
    const unsigned short* aH = p.xhi + (size_t)(vrt ? nr : nc) * 128;
    const unsigned short* aL = p.xlo + (size_t)(vrt ? nr : nc) * 128;
    const unsigned short* bH = p.xhi + (size_t)(vrt ? nc : nr) * 128;
    const unsigned short* bL = p.xlo + (size_t)(vrt ? nc : nr) * 128;
    const float* ep = p.ef + (size_t)ec * 128;
#pragma unroll
    for (int kt = 0; kt < 12; kt++) {
      const int cur = kt & 1;
      const int nxt = cur ^ 1;
      stageW(kt + 1, nxt);   // W1[kt+1] or (kt=11) W2[0]
      const int kc = (kt & 3) * 32 + acol;
      f16x8 ah, al;
      if (kt < 4)      { ah = *(const f16x8*)(aH + kc); al = *(const f16x8*)(aL + kc); }
      else if (kt < 8) { ah = *(const f16x8*)(bH + kc); al = *(const f16x8*)(bL + kc); }
      else {
        union { unsigned short u[8]; f16x8 v; } th, tl;
#pragma unroll
        for (int j = 0; j < 8; j++) {
          float v = ep[kc + j];
          th.u[j] = f2h(v); tl.u[j] = loPart(v, th.u[j]);
        }
        ah = th.v; al = tl.v;
      }
#pragma unroll
      for (int nt = 0; nt < 8; nt++) {
        f16x8 bh = *(const f16x8*)&wbuf[cur * 8192 + nt * 512 + lane * 8];
        f16x8 bl = *(const f16x8*)&wbuf[cur * 8192 + 4096 + nt * 512 + lane * 8];
        mfma4(ah, al, bh, bl, acc1[nt], acc1x[nt], acc1y[nt]);
      }
      __syncthreads();
    }
  } else {
#pragma unroll
    for (int kt = 0; kt < K1T; kt++) {
      int t = kt >> 2;
      int so = swz(arow, (kt & 3) * 32 + acol);
      f16x8 ah = *(const f16x8*)&HI(t)[so];
      f16x8 al = *(const f16x8*)&LO(t)[so];
#pragma unroll
      for (int nt = 0; nt < 8; nt++) {
        f16x8 bh = *(const f16x8*)&p.w1h[(size_t)(kt * 8 + nt) * 512 + lane * 8];
        f16x8 bl = *(const f16x8*)&p.w1l[(size_t)(kt * 8 + nt) * 512 + lane * 8];
        mfma4(ah, al, bh, bl, acc1[nt], acc1x[nt], acc1y[nt]);
      }
    }
  }

  // ---------------- h1 = relu(acc + b1) -> LDS hi/lo (region vrt) ----------
  // Each wave writes/reads only its own 16-row band inside its variant region.
  float b1c[8];
#pragma unroll
  for (int nt = 0; nt < 8; nt++) b1c[nt] = p.b1[nt * 16 + l15];
#pragma unroll
  for (int nt = 0; nt < 8; nt++) {
#pragma unroll
    for (int r = 0; r < 4; r++) {
      int row = w4 * 16 + (lg << 2) + r;
      int col = nt * 16 + l15;
      int off = swz(row, col);
      float v = combine3(acc1[nt][r], acc1x[nt][r], acc1y[nt][r], b1c[nt]);
      v = v > 0.f ? v : 0.f;
      unsigned short hi = f2h(v);
      HI(vrt)[off] = hi; LO(vrt)[off] = loPart(v, hi);
    }
  }

  if constexpr (MODE != 4) {
    // ---------------- layer 2 (K=128 from h1 in LDS region vrt) ----------------
    f32x4 acc2[8], acc2x[8], acc2y[8];
#pragma unroll
    for (int nt = 0; nt < 8; nt++) { acc2[nt] = zz; acc2x[nt] = zz; acc2y[nt] = zz; }
#pragma unroll
    for (int kt = 0; kt < 4; kt++) {
      if constexpr (MODE == 2) {
        const int cur = (12 + kt) & 1;
        if (kt < 3) stageW(13 + kt, cur ^ 1);   // W2[kt+1] (steps 13,14,15)
        int so = swz(arow, kt * 32 + acol);
        f16x8 ah = *(const f16x8*)&HI(vrt)[so];
        f16x8 al = *(const f16x8*)&LO(vrt)[so];
#pragma unroll
        for (int nt = 0; nt < 8; nt++) {
          f16x8 bh = *(const f16x8*)&wbuf[cur * 8192 + nt * 512 + lane * 8];
          f16x8 bl = *(const f16x8*)&wbuf[cur * 8192 + 4096 + nt * 512 + lane * 8];
          mfma4(ah, al, bh, bl, acc2[nt], acc2x[nt], acc2y[nt]);
        }
        if (kt < 3) __syncthreads();
      } else {
        int so = swz(arow, kt * 32 + acol);
        f16x8 ah = *(const f16x8*)&HI(vrt)[so];
        f16x8 al = *(const f16x8*)&LO(vrt)[so];
#pragma unroll
        for (int nt = 0; nt < 8; nt++) {
          f16x8 bh = *(const f16x8*)&p.w2h[(size_t)(kt * 8 + nt) * 512 + lane * 8];
          f16x8 bl = *(const f16x8*)&p.w2l[(size_t)(kt * 8 + nt) * 512 + lane * 8];
          mfma4(ah, al, bh, bl, acc2[nt], acc2x[nt], acc2y[nt]);
        }
      }
    }

    // ---------------- LayerNorm epilogue (f64 statistics) ----------------
    float b2c[8], gc[8], bec[8];
#pragma unroll
    for (int nt = 0; nt < 8; nt++) {
      int c = nt * 16 + l15;
      b2c[nt] = p.b2[c]; gc[nt] = p.g[c]; bec[nt] = p.be[c];
    }
    {
      double sum[4] = {0.0, 0.0, 0.0, 0.0};
#pragma unroll
      for (int nt = 0; nt < 8; nt++)
#pragma unroll
        for (int r = 0; r < 4; r++) {
          acc2[nt][r] = combine3(acc2[nt][r], acc2x[nt][r], acc2y[nt][r], b2c[nt]);
          sum[r] += (double)acc2[nt][r];
        }
#pragma unroll
      for (int r = 0; r < 4; r++) {
#pragma unroll
        for (int m = 1; m < 16; m <<= 1) sum[r] += __shfl_xor(sum[r], m);
        sum[r] *= (1.0 / 128.0);
      }
      double vs[4] = {0.0, 0.0, 0.0, 0.0};
#pragma unroll
      for (int nt = 0; nt < 8; nt++)
#pragma unroll
        for (int r = 0; r < 4; r++) {
          double d = (double)acc2[nt][r] - sum[r];
          vs[r] += d * d;
        }
#pragma unroll
      for (int r = 0; r < 4; r++) {
#pragma unroll
        for (int m = 1; m < 16; m <<= 1) vs[r] += __shfl_xor(vs[r], m);
        vs[r] = 1.0 / sqrt(vs[r] * (1.0 / 128.0) + 1e-5);
      }
#pragma unroll
      for (int nt = 0; nt < 8; nt++)
#pragma unroll
        for (int r = 0; r < 4; r++)
          acc2[nt][r] = (float)(((double)acc2[nt][r] - sum[r]) * vs[r]) * gc[nt] + bec[nt];
    }

    // MODE 2: order all ef reads (layer 1) before variant-1's in-place ef
    // writes below — WAR hazard protection within the block.
    if constexpr (MODE == 2) __syncthreads();

    // ---------------- writeback ----------------
#pragma unroll
    for (int r = 0; r < 4; r++) {
      int idx = r0 + w4 * 16 + (lg << 2) + r;
      if (idx >= p.nrows) continue;
      if constexpr (MODE == 0) {
        float* xr = p.xf + (size_t)idx * 128;
        unsigned short* xh_ = p.xhi_out + (size_t)idx * 128;
        unsigned short* xl_ = p.xlo_out + (size_t)idx * 128;
#pragma unroll
        for (int nt = 0; nt < 8; nt++) {
          int c = nt * 16 + l15; float v = acc2[nt][r];
          xr[c] = v;
          unsigned short hi = f2h(v);
          xh_[c] = hi; xl_[c] = loPart(v, hi);
        }
      } else if constexpr (MODE == 1) {
        float* er = p.ef + (size_t)idx * 128;
#pragma unroll
        for (int nt = 0; nt < 8; nt++) er[nt * 16 + l15] = acc2[nt][r];
      } else if constexpr (MODE == 3) {
        float* xr = p.xf + (size_t)idx * 128;
        unsigned short* xh_ = p.xhi_out + (size_t)idx * 128;
        unsigned short* xl_ = p.xlo_out + (size_t)idx * 128;
#pragma unroll
        for (int nt = 0; nt < 8; nt++) {
          int c = nt * 16 + l15;
          float v = acc2[nt][r] + xr[c];   // residual from f32 master
          xr[c] = v;
          unsigned short hi = f2h(v);
          xh_[c] = hi; xl_[c] = loPart(v, hi);
        }
      } else {  // MODE 2: variant 0 scatters msg (int32 2^22, deterministic);
                //          variant 1 updates eh in place
        if (vrt == 0) {
          int tgt = p.coli[idx];
          int* ar = p.aggi + (size_t)tgt * 128;
#pragma unroll
          for (int nt = 0; nt < 8; nt++) {
            int q = __double2int_rn((double)acc2[nt][r] * AGG_SCALE_D);
            atomicAdd(&ar[nt * 16 + l15], q);
          }
        } else {
          float* er = p.ef + (size_t)idx * 128;
#pragma unroll
          for (int nt = 0; nt < 8; nt++) {
            int c = nt * 16 + l15;
            er[c] = acc2[nt][r] + er[c];
          }
        }
      }
    }
  } else {
    // ---------------- decoder tail: out = h1 @ w2f + b2 (OUT=3, f64 acc) -----
    __syncthreads();   // tail reads h1 rows written by other waves
    if (tid < 192) {
      int row = tid / 3, oc = tid - row * 3;
      int n = r0 + row;
      if (n < p.nrows) {
        double s = (double)w2s[384 + oc];
        for (int k = 0; k < 128; k++) {
          int off = swz(row, k);
          double h = (double)h2f(HI(0)[off]) + (double)h2f(LO(0)[off]) * LO_INV_D;
          s += h * (double)w2s[k * 3 + oc];
        }
        p.out[(size_t)n * 3 + oc] = (float)s;
      }
    }
  }
}

extern "C" void kernel_launch(void* const* d_in, const int* in_sizes, int n_in,
                              void* d_out, int out_size, void* d_ws, size_t ws_size,
                              hipStream_t stream) {
  if (n_in < 31) return;
  const int N = in_sizes[0] / 15;
  const int E = in_sizes[1] / 7;
  const float* x        = (const float*)d_in[0];
  const float* ein      = (const float*)d_in[1];
  const int*   eidx     = (const int*)d_in[2];
  const float* enc_n_w1 = (const float*)d_in[3];
  const float* enc_n_b1 = (const float*)d_in[4];
  const float* enc_n_w2 = (const float*)d_in[5];
  const float* enc_n_b2 = (const float*)d_in[6];
  const float* enc_n_g  = (const float*)d_in[7];
  const float* enc_n_be = (const float*)d_in[8];
  const float* enc_e_w1 = (const float*)d_in[9];
  const float* enc_e_b1 = (const float*)d_in[10];
  const float* enc_e_w2 = (const float*)d_in[11];
  const float* enc_e_b2 = (const float*)d_in[12];
  const float* enc_e_g  = (const float*)d_in[13];
  const float* enc_e_be = (const float*)d_in[14];
  const float* pe_w1    = (const float*)d_in[15];
  const float* pe_b1    = (const float*)d_in[16];
  const float* pe_w2    = (const float*)d_in[17];
  const float* pe_b2    = (const float*)d_in[18];
  const float* pe_g     = (const float*)d_in[19];
  const float* pe_be    = (const float*)d_in[20];
  const float* pn_w1    = (const float*)d_in[21];
  const float* pn_b1    = (const float*)d_in[22];
  const float* pn_w2    = (const float*)d_in[23];
  const float* pn_b2    = (const float*)d_in[24];
  const float* pn_g     = (const float*)d_in[25];
  const float* pn_be    = (const float*)d_in[26];
  const float* dec_w1   = (const float*)d_in[27];
  const float* dec_b1   = (const float*)d_in[28];
  const float* dec_w2   = (const float*)d_in[29];
  const float* dec_b2   = (const float*)d_in[30];

  char* ws = (char*)d_ws;
  size_t off = 0;
  auto carve = [&](size_t bytes) -> void* {
    void* pp = ws + off; off += (bytes + 255) & ~(size_t)255; return pp;
  };
  float* xh            = (float*)carve((size_t)N * 128 * 4);
  unsigned short* xhi  = (unsigned short*)carve((size_t)N * 128 * 2);
  unsigned short* xlo  = (unsigned short*)carve((size_t)N * 128 * 2);
  float* eh            = (float*)carve((size_t)E * 128 * 4);
  int* aggi            = (int*)carve((size_t)N * 128 * 4);

  const int ktab[17] = {15, 128, 7, 128, 384, 384, 384, 128, 128, 128,
                        256, 256, 256, 128, 128, 128, 128};
  unsigned short* pk[17];
  for (int i = 0; i < 17; i++) {
    int kt = (ktab[i] + 31) / 32;
    pk[i] = (unsigned short*)carve((size_t)2 * kt * 8 * 512 * 2);  // hi+lo
  }
  if (off > ws_size) return;  // workspace too small -> fail validation loudly

  RepackParams rp;
  const float* wsrc[17] = {enc_n_w1, enc_n_w2, enc_e_w1, enc_e_w2,
                           pe_w1, pe_w1 + 384 * 128, pe_w1 + 2 * 384 * 128,
                           pe_w2, pe_w2 + 128 * 128, pe_w2 + 2 * 128 * 128,
                           pn_w1, pn_w1 + 256 * 128, pn_w1 + 2 * 256 * 128,
                           pn_w2, pn_w2 + 128 * 128, pn_w2 + 2 * 128 * 128,
                           dec_w1};
  for (int i = 0; i < 17; i++) {
    rp.it[i].src = wsrc[i]; rp.it[i].dst = pk[i];
    rp.it[i].K = ktab[i]; rp.it[i].Kt = (ktab[i] + 31) / 32;
  }
  repack_kernel<<<dim3(96, 17), 256, 0, stream>>>(rp);

  auto wlo = [&](int i) { return pk[i] + (size_t)((ktab[i] + 31) / 32) * 8 * 512; };
  const int gN = (N + 63) / 64, gE = (E + 63) / 64, gE96 = (E + 95) / 96;

  {  // node encoder
    KParams kp{};
    kp.w1h = pk[0]; kp.w1l = wlo(0); kp.w2h = pk[1]; kp.w2l = wlo(1);
    kp.b1 = enc_n_b1; kp.b2 = enc_n_b2; kp.g = enc_n_g; kp.be = enc_n_be;
    kp.srcA = x; kp.xf = xh; kp.xhi_out = xhi; kp.xlo_out = xlo;
    kp.nrows = N; kp.kin = 15;
    gnn_kernel<0><<<gN, 256, 0, stream>>>(kp);
  }
  {  // edge encoder
    KParams kp{};
    kp.w1h = pk[2]; kp.w1l = wlo(2); kp.w2h = pk[3]; kp.w2l = wlo(3);
    kp.b1 = enc_e_b1; kp.b2 = enc_e_b2; kp.g = enc_e_g; kp.be = enc_e_be;
    kp.srcA = ein; kp.ef = eh; kp.nrows = E; kp.kin = 7;
    gnn_kernel<1><<<gE, 256, 0, stream>>>(kp);
  }
  for (int i = 0; i < 3; i++) {
    hipMemsetAsync(aggi, 0, (size_t)N * 128 * 4, stream);
    {  // edge processor (768 threads: 6 msg waves + 6 edge-update waves)
      KParams kp{};
      kp.w1h = pk[4 + i]; kp.w1l = wlo(4 + i);
      kp.w2h = pk[7 + i]; kp.w2l = wlo(7 + i);
      kp.b1 = pe_b1 + i * 128; kp.b2 = pe_b2 + i * 128;
      kp.g = pe_g + i * 128; kp.be = pe_be + i * 128;
      kp.xhi = xhi; kp.xlo = xlo; kp.ef = eh;
      kp.rowi = eidx; kp.coli = eidx + E;
      kp.aggi = aggi; kp.nrows = E;
      gnn_kernel<2><<<gE96, 768, 0, stream>>>(kp);
    }
    {  // node processor (reads deterministic int32 aggregate via double)
      KParams kp{};
      kp.w1h = pk[10 + i]; kp.w1l = wlo(10 + i);
      kp.w2h = pk[13 + i]; kp.w2l = wlo(13 + i);
      kp.b1 = pn_b1 + i * 128; kp.b2 = pn_b2 + i * 128;
      kp.g = pn_g + i * 128; kp.be = pn_be + i * 128;
      kp.aggi = aggi; kp.xhi = xhi; kp.xlo = xlo;
      kp.xf = xh; kp.xhi_out = xhi; kp.xlo_out = xlo; kp.nrows = N;
      gnn_kernel<3><<<gN, 256, 0, stream>>>(kp);
    }
  }
  {  // decoder
    KParams kp{};
    kp.w1h = pk[16]; kp.w1l = wlo(16); kp.b1 = dec_b1;
    kp.xhi = xhi; kp.xlo = xlo; kp.w2f = dec_w2; kp.b2f = dec_b2;
    kp.out = (float*)d_out; kp.nrows = N;
    gnn_kernel<4><<<gN, 256, 0, stream>>>(kp);
  }
}

// Round 21
// 1884.421 us; speedup vs baseline: 1.1507x; 1.0037x over previous
//
#include <hip/hip_runtime.h>
#include <stdint.h>
#include <math.h>

#define DEVI __device__ __forceinline__

typedef __attribute__((ext_vector_type(8))) _Float16 f16x8;
typedef __attribute__((ext_vector_type(4))) float f32x4;

#define LO_SCALE 2048.0f
#define LO_INV (1.0f / 2048.0f)
#define LO_INV_D (1.0 / 2048.0)
// int32 fixed-point aggregation at 2^22, quantized/read back through double:
// per-message error <= 1.2e-7 absolute; integer sum is order-exact.
#define AGG_SCALE_D 4194304.0
#define AGG_INV_D (1.0 / 4194304.0)

DEVI unsigned short f2h(float f) {
  union { _Float16 h; unsigned short u; } v; v.h = (_Float16)f; return v.u;
}
DEVI float h2f(unsigned short u) {
  union { unsigned short u; _Float16 h; } v; v.u = u; return (float)v.h;
}
DEVI unsigned short loPart(float v, unsigned short hi) {
  return f2h((v - h2f(hi)) * LO_SCALE);
}
DEVI f32x4 mfma16(f16x8 a, f16x8 b, f32x4 c) {
  return __builtin_amdgcn_mfma_f32_16x16x32_f16(a, b, c, 0, 0, 0);
}
// Full 4-term pair product: acc += Ah*Bh ; accx += Ah*Bl + Al*Bh ; accy += Al*Bl
// (accx scaled x2048, accy x2048^2). Combine in f64: ~f32-exact GEMM.
DEVI void mfma4(f16x8 ah, f16x8 al, f16x8 bh, f16x8 bl,
                f32x4& acc, f32x4& accx, f32x4& accy) {
  acc  = mfma16(ah, bh, acc);
  accx = mfma16(ah, bl, accx);
  accx = mfma16(al, bh, accx);
  accy = mfma16(al, bl, accy);
}
DEVI float combine3(float a, float ax, float ay, float b) {
  return (float)((double)a + ((double)ax + (double)ay * LO_INV_D) * LO_INV_D + (double)b);
}
// swizzled element offset inside one [rows][128] fp16 tile (row stride 256B).
DEVI int swz(int row, int col) { return row * 128 + (col ^ ((row & 7) << 3)); }

struct KParams {
  const unsigned short* w1h; const unsigned short* w1l;
  const unsigned short* w2h; const unsigned short* w2l;
  const float* b1; const float* b2; const float* g; const float* be;
  const float* srcA;                 // ENC: x/e
  const unsigned short* xhi;         // fp16 hi mirror of xh
  const unsigned short* xlo;         // fp16 lo mirror (x2048)
  float* xf;                         // xh f32 master
  float* ef;                         // eh f32 master
  unsigned short* xhi_out; unsigned short* xlo_out;
  const int* rowi; const int* coli;
  int* aggi;                         // [N,128] int32 2^22 fixed-point aggregate
  float* out;
  const float* w2f; const float* b2f;  // decoder layer-2 (f32)
  int nrows; int kin;
};

struct RepackItem { const float* src; unsigned short* dst; int K; int Kt; };
struct RepackParams { RepackItem it[17]; };

// Pack W [K][128] f32 -> fp16 hi/lo MFMA B-fragments. hi at [0, Kt*8*512),
// lo (x2048) at [Kt*8*512, 2*Kt*8*512).
__global__ __launch_bounds__(256) void repack_kernel(RepackParams rp) {
  const RepackItem w = rp.it[blockIdx.y];
  const int f = blockIdx.x;
  if (f >= w.Kt * 8) return;
  const int kt = f >> 3, nt = f & 7;
  const size_t loOff = (size_t)w.Kt * 8 * 512;
  for (int s = threadIdx.x; s < 512; s += 256) {
    int ln = s >> 3, j = s & 7;
    int k = kt * 32 + ((ln >> 4) << 3) + j;
    int c = nt * 16 + (ln & 15);
    float v = (k < w.K) ? w.src[(size_t)k * 128 + c] : 0.f;
    unsigned short hi = f2h(v);
    w.dst[(size_t)f * 512 + s] = hi;
    w.dst[loOff + (size_t)f * 512 + s] = loPart(v, hi);
  }
}

// ---------------- edge processor (standalone, occupancy-pinned) ----------------
// 768 threads (12 waves) over 96 edges; waves 0-5 = msg variant (bands 0-5),
// waves 6-11 = edge-update. amdgpu_waves_per_eu(3,3) pins the allocator's
// occupancy target to what the 128KB LDS actually allows (3 waves/EU), raising
// the VGPR budget to ~170 so the 96-reg mfma4 accumulator set stops spilling
// (R16/R20: 84 VGPR + 120MB scratch traffic). Instruction semantics identical
// to R20's MODE 2 -> output bit-identical (absmax 0.0078125).
__global__ __attribute__((amdgpu_flat_work_group_size(768, 768)))
           __attribute__((amdgpu_waves_per_eu(3, 3)))
void edge_kernel(KParams p) {
  constexpr int NT = 768;
  constexpr int REG = 12288;                       // elems per hi (or lo) region
  __shared__ __align__(16) unsigned short stA[2 * 2 * REG];   // h1 hi/lo x 2 variants
  __shared__ __align__(16) unsigned short wbuf[16384];        // 2 x 16KB

  const int tid = threadIdx.x;
  const int lane = tid & 63;
  const int wave = tid >> 6;
  const int w4 = wave % 6;        // 16-row band index
  const int vrt = wave / 6;       // variant: 0=msg 1=edge-update
  const int r0 = blockIdx.x * 96;
  const int l15 = lane & 15;
  const int lg = lane >> 4;

  auto HI = [&](int t) { return stA + 2 * t * REG; };
  auto LO = [&](int t) { return stA + 2 * t * REG + REG; };

  auto stageW = [&](int s, int buf) {
    const unsigned short* h = (s < 12) ? p.w1h + s * 4096 : p.w2h + (s - 12) * 4096;
    const unsigned short* l = (s < 12) ? p.w1l + s * 4096 : p.w2l + (s - 12) * 4096;
    for (int i = tid; i < 1024; i += NT) {
      *(f16x8*)&wbuf[buf * 8192 + i * 8] =
          *(const f16x8*)((i < 512) ? h + i * 8 : l + (i - 512) * 8);
    }
  };

  stageW(0, 0);
  __syncthreads();

  // ---------------- layer 1 (K = 12*32) ----------------
  const f32x4 zz = {0.f, 0.f, 0.f, 0.f};
  f32x4 acc1[8], acc1x[8], acc1y[8];
#pragma unroll
  for (int nt = 0; nt < 8; nt++) { acc1[nt] = zz; acc1x[nt] = zz; acc1y[nt] = zz; }
  const int arow = w4 * 16 + l15;
  const int acol = lg << 3;

  const int ridx = r0 + arow;
  const int ec = (ridx < p.nrows) ? ridx : 0;   // clamped (outputs discarded)
  const int nc = p.coli[ec], nr = p.rowi[ec];
  // msg variant: [Xc, Xr, Ee] ; edge-update variant: [Xr, Xc, Ee]
  const unsigned short* aH = p.xhi + (size_t)(vrt ? nr : nc) * 128;
  const unsigned short* aL = p.xlo + (size_t)(vrt ? nr : nc) * 128;
  const unsigned short* bH = p.xhi + (size_t)(vrt ? nc : nr) * 128;
  const unsigned short* bL = p.xlo + (size_t)(vrt ? nc : nr) * 128;
  const float* ep = p.ef + (size_t)ec * 128;
#pragma unroll
  for (int kt = 0; kt < 12; kt++) {
    const int cur = kt & 1;
    stageW(kt + 1, cur ^ 1);   // W1[kt+1] or (kt=11) W2[0]
    const int kc = (kt & 3) * 32 + acol;
    f16x8 ah, al;
    if (kt < 4)      { ah = *(const f16x8*)(aH + kc); al = *(const f16x8*)(aL + kc); }
    else if (kt < 8) { ah = *(const f16x8*)(bH + kc); al = *(const f16x8*)(bL + kc); }
    else {
      union { unsigned short u[8]; f16x8 v; } th, tl;
#pragma unroll
      for (int j = 0; j < 8; j++) {
        float v = ep[kc + j];
        th.u[j] = f2h(v); tl.u[j] = loPart(v, th.u[j]);
      }
      ah = th.v; al = tl.v;
    }
#pragma unroll
    for (int nt = 0; nt < 8; nt++) {
      f16x8 bh = *(const f16x8*)&wbuf[cur * 8192 + nt * 512 + lane * 8];
      f16x8 bl = *(const f16x8*)&wbuf[cur * 8192 + 4096 + nt * 512 + lane * 8];
      mfma4(ah, al, bh, bl, acc1[nt], acc1x[nt], acc1y[nt]);
    }
    __syncthreads();
  }

  // ---------------- h1 = relu(acc + b1) -> LDS hi/lo (region vrt) ----------
  float b1c[8];
#pragma unroll
  for (int nt = 0; nt < 8; nt++) b1c[nt] = p.b1[nt * 16 + l15];
#pragma unroll
  for (int nt = 0; nt < 8; nt++) {
#pragma unroll
    for (int r = 0; r < 4; r++) {
      int row = w4 * 16 + (lg << 2) + r;
      int col = nt * 16 + l15;
      int off = swz(row, col);
      float v = combine3(acc1[nt][r], acc1x[nt][r], acc1y[nt][r], b1c[nt]);
      v = v > 0.f ? v : 0.f;
      unsigned short hi = f2h(v);
      HI(vrt)[off] = hi; LO(vrt)[off] = loPart(v, hi);
    }
  }

  // ---------------- layer 2 (K=128 from h1 in LDS region vrt) ----------------
  f32x4 acc2[8], acc2x[8], acc2y[8];
#pragma unroll
  for (int nt = 0; nt < 8; nt++) { acc2[nt] = zz; acc2x[nt] = zz; acc2y[nt] = zz; }
#pragma unroll
  for (int kt = 0; kt < 4; kt++) {
    const int cur = (12 + kt) & 1;
    if (kt < 3) stageW(13 + kt, cur ^ 1);   // W2[kt+1] (steps 13,14,15)
    int so = swz(arow, kt * 32 + acol);
    f16x8 ah = *(const f16x8*)&HI(vrt)[so];
    f16x8 al = *(const f16x8*)&LO(vrt)[so];
#pragma unroll
    for (int nt = 0; nt < 8; nt++) {
      f16x8 bh = *(const f16x8*)&wbuf[cur * 8192 + nt * 512 + lane * 8];
      f16x8 bl = *(const f16x8*)&wbuf[cur * 8192 + 4096 + nt * 512 + lane * 8];
      mfma4(ah, al, bh, bl, acc2[nt], acc2x[nt], acc2y[nt]);
    }
    if (kt < 3) __syncthreads();
  }

  // ---------------- LayerNorm epilogue (f64 statistics) ----------------
  float b2c[8], gc[8], bec[8];
#pragma unroll
  for (int nt = 0; nt < 8; nt++) {
    int c = nt * 16 + l15;
    b2c[nt] = p.b2[c]; gc[nt] = p.g[c]; bec[nt] = p.be[c];
  }
  {
    double sum[4] = {0.0, 0.0, 0.0, 0.0};
#pragma unroll
    for (int nt = 0; nt < 8; nt++)
#pragma unroll
      for (int r = 0; r < 4; r++) {
        acc2[nt][r] = combine3(acc2[nt][r], acc2x[nt][r], acc2y[nt][r], b2c[nt]);
        sum[r] += (double)acc2[nt][r];
      }
#pragma unroll
    for (int r = 0; r < 4; r++) {
#pragma unroll
      for (int m = 1; m < 16; m <<= 1) sum[r] += __shfl_xor(sum[r], m);
      sum[r] *= (1.0 / 128.0);
    }
    double vs[4] = {0.0, 0.0, 0.0, 0.0};
#pragma unroll
    for (int nt = 0; nt < 8; nt++)
#pragma unroll
      for (int r = 0; r < 4; r++) {
        double d = (double)acc2[nt][r] - sum[r];
        vs[r] += d * d;
      }
#pragma unroll
    for (int r = 0; r < 4; r++) {
#pragma unroll
      for (int m = 1; m < 16; m <<= 1) vs[r] += __shfl_xor(vs[r], m);
      vs[r] = 1.0 / sqrt(vs[r] * (1.0 / 128.0) + 1e-5);
    }
#pragma unroll
    for (int nt = 0; nt < 8; nt++)
#pragma unroll
      for (int r = 0; r < 4; r++)
        acc2[nt][r] = (float)(((double)acc2[nt][r] - sum[r]) * vs[r]) * gc[nt] + bec[nt];
  }

  // order all ef reads (layer 1) before variant-1's in-place ef writes below.
  __syncthreads();

  // ---------------- writeback ----------------
#pragma unroll
  for (int r = 0; r < 4; r++) {
    int idx = r0 + w4 * 16 + (lg << 2) + r;
    if (idx >= p.nrows) continue;
    if (vrt == 0) {
      int tgt = p.coli[idx];
      int* ar = p.aggi + (size_t)tgt * 128;
#pragma unroll
      for (int nt = 0; nt < 8; nt++) {
        int q = __double2int_rn((double)acc2[nt][r] * AGG_SCALE_D);
        atomicAdd(&ar[nt * 16 + l15], q);
      }
    } else {
      float* er = p.ef + (size_t)idx * 128;
#pragma unroll
      for (int nt = 0; nt < 8; nt++) {
        int c = nt * 16 + l15;
        er[c] = acc2[nt][r] + er[c];
      }
    }
  }
}

// Modes: 0=node-encoder 1=edge-encoder 3=node-processor 4=decoder
template <int MODE>
__global__ __launch_bounds__(256, 2)
void gnn_kernel(KParams p) {
  constexpr int NT = 256;
  constexpr int REG = 8192;                        // elems per hi (or lo) region
  constexpr int NREG = (MODE == 3) ? 2 : 1;
  __shared__ __align__(16) unsigned short stA[NREG * 2 * REG];
  __shared__ float w2s[(MODE == 4) ? 392 : 1];

  const int tid = threadIdx.x;
  const int lane = tid & 63;
  const int wave = tid >> 6;
  const int w4 = wave;            // 16-row band index
  const int r0 = blockIdx.x * 64;
  const int l15 = lane & 15;
  const int lg = lane >> 4;

  auto HI = [&](int t) { return stA + 2 * t * REG; };
  auto LO = [&](int t) { return stA + 2 * t * REG + REG; };

  // ---------------- stage inputs (fp16 hi/lo, swizzled) ----------------
  if constexpr (MODE == 3) {
    for (int s = tid; s < 1024; s += NT) {
      int row = s >> 4, cc = (s & 15) * 8;
      int n = r0 + row;
      int off = swz(row, cc);
      if (n < p.nrows) {
        const int* ap = p.aggi + (size_t)n * 128 + cc;
        union { unsigned short u[8]; f16x8 v; } th, tl;
#pragma unroll
        for (int j = 0; j < 8; j++) {
          float v = (float)((double)ap[j] * AGG_INV_D);   // exact int->double->f32
          th.u[j] = f2h(v); tl.u[j] = loPart(v, th.u[j]);
        }
        *(f16x8*)&HI(0)[off] = th.v; *(f16x8*)&LO(0)[off] = tl.v;
        *(f16x8*)&HI(1)[off] = *(const f16x8*)(p.xhi + (size_t)n * 128 + cc);
        *(f16x8*)&LO(1)[off] = *(const f16x8*)(p.xlo + (size_t)n * 128 + cc);
      } else {
        f16x8 z = {0,0,0,0,0,0,0,0};
        *(f16x8*)&HI(0)[off] = z; *(f16x8*)&LO(0)[off] = z;
        *(f16x8*)&HI(1)[off] = z; *(f16x8*)&LO(1)[off] = z;
      }
    }
  } else if constexpr (MODE == 0 || MODE == 1) {
    for (int s = tid; s < 256; s += NT) {
      int row = s >> 2, cc = (s & 3) * 8;
      int n = r0 + row;
      union { unsigned short u[8]; f16x8 v; } th, tl;
#pragma unroll
      for (int j = 0; j < 8; j++) {
        int k = cc + j;
        float v = (n < p.nrows && k < p.kin) ? p.srcA[(size_t)n * p.kin + k] : 0.f;
        th.u[j] = f2h(v); tl.u[j] = loPart(v, th.u[j]);
      }
      int off = swz(row, cc);
      *(f16x8*)&HI(0)[off] = th.v; *(f16x8*)&LO(0)[off] = tl.v;
    }
  } else if constexpr (MODE == 4) {
    for (int s = tid; s < 1024; s += NT) {
      int row = s >> 4, cc = (s & 15) * 8;
      int n = r0 + row;
      int off = swz(row, cc);
      f16x8 z = {0,0,0,0,0,0,0,0};
      if (n < p.nrows) {
        *(f16x8*)&HI(0)[off] = *(const f16x8*)(p.xhi + (size_t)n * 128 + cc);
        *(f16x8*)&LO(0)[off] = *(const f16x8*)(p.xlo + (size_t)n * 128 + cc);
      } else { *(f16x8*)&HI(0)[off] = z; *(f16x8*)&LO(0)[off] = z; }
    }
    for (int s = tid; s < 387; s += NT) w2s[s] = (s < 384) ? p.w2f[s] : p.b2f[s - 384];
  }
  __syncthreads();

  // ---------------- layer 1 (K = K1T*32) ----------------
  constexpr int K1T = (MODE == 3) ? 8 : (MODE == 4) ? 4 : 1;
  const f32x4 zz = {0.f, 0.f, 0.f, 0.f};
  f32x4 acc1[8], acc1x[8], acc1y[8];
#pragma unroll
  for (int nt = 0; nt < 8; nt++) { acc1[nt] = zz; acc1x[nt] = zz; acc1y[nt] = zz; }
  const int arow = w4 * 16 + l15;
  const int acol = lg << 3;

#pragma unroll
  for (int kt = 0; kt < K1T; kt++) {
    int t = kt >> 2;
    int so = swz(arow, (kt & 3) * 32 + acol);
    f16x8 ah = *(const f16x8*)&HI(t)[so];
    f16x8 al = *(const f16x8*)&LO(t)[so];
#pragma unroll
    for (int nt = 0; nt < 8; nt++) {
      f16x8 bh = *(const f16x8*)&p.w1h[(size_t)(kt * 8 + nt) * 512 + lane * 8];
      f16x8 bl = *(const f16x8*)&p.w1l[(size_t)(kt * 8 + nt) * 512 + lane * 8];
      mfma4(ah, al, bh, bl, acc1[nt], acc1x[nt], acc1y[nt]);
    }
  }

  // ---------------- h1 = relu(acc + b1) -> LDS hi/lo (region 0) ----------
  float b1c[8];
#pragma unroll
  for (int nt = 0; nt < 8; nt++) b1c[nt] = p.b1[nt * 16 + l15];
#pragma unroll
  for (int nt = 0; nt < 8; nt++) {
#pragma unroll
    for (int r = 0; r < 4; r++) {
      int row = w4 * 16 + (lg << 2) + r;
      int col = nt * 16 + l15;
      int off = swz(row, col);
      float v = combine3(acc1[nt][r], acc1x[nt][r], acc1y[nt][r], b1c[nt]);
      v = v > 0.f ? v : 0.f;
      unsigned short hi = f2h(v);
      HI(0)[off] = hi; LO(0)[off] = loPart(v, hi);
    }
  }

  if constexpr (MODE != 4) {
    // ---------------- layer 2 (K=128 from h1 in LDS) ----------------
    f32x4 acc2[8], acc2x[8], acc2y[8];
#pragma unroll
    for (int nt = 0; nt < 8; nt++) { acc2[nt] = zz; acc2x[nt] = zz; acc2y[nt] = zz; }
#pragma unroll
    for (int kt = 0; kt < 4; kt++) {
      int so = swz(arow, kt * 32 + acol);
      f16x8 ah = *(const f16x8*)&HI(0)[so];
      f16x8 al = *(const f16x8*)&LO(0)[so];
#pragma unroll
      for (int nt = 0; nt < 8; nt++) {
        f16x8 bh = *(const f16x8*)&p.w2h[(size_t)(kt * 8 + nt) * 512 + lane * 8];
        f16x8 bl = *(const f16x8*)&p.w2l[(size_t)(kt * 8 + nt) * 512 + lane * 8];
        mfma4(ah, al, bh, bl, acc2[nt], acc2x[nt], acc2y[nt]);
      }
    }

    // ---------------- LayerNorm epilogue (f64 statistics) ----------------
    float b2c[8], gc[8], bec[8];
#pragma unroll
    for (int nt = 0; nt < 8; nt++) {
      int c = nt * 16 + l15;
      b2c[nt] = p.b2[c]; gc[nt] = p.g[c]; bec[nt] = p.be[c];
    }
    {
      double sum[4] = {0.0, 0.0, 0.0, 0.0};
#pragma unroll
      for (int nt = 0; nt < 8; nt++)
#pragma unroll
        for (int r = 0; r < 4; r++) {
          acc2[nt][r] = combine3(acc2[nt][r], acc2x[nt][r], acc2y[nt][r], b2c[nt]);
          sum[r] += (double)acc2[nt][r];
        }
#pragma unroll
      for (int r = 0; r < 4; r++) {
#pragma unroll
        for (int m = 1; m < 16; m <<= 1) sum[r] += __shfl_xor(sum[r], m);
        sum[r] *= (1.0 / 128.0);
      }
      double vs[4] = {0.0, 0.0, 0.0, 0.0};
#pragma unroll
      for (int nt = 0; nt < 8; nt++)
#pragma unroll
        for (int r = 0; r < 4; r++) {
          double d = (double)acc2[nt][r] - sum[r];
          vs[r] += d * d;
        }
#pragma unroll
      for (int r = 0; r < 4; r++) {
#pragma unroll
        for (int m = 1; m < 16; m <<= 1) vs[r] += __shfl_xor(vs[r], m);
        vs[r] = 1.0 / sqrt(vs[r] * (1.0 / 128.0) + 1e-5);
      }
#pragma unroll
      for (int nt = 0; nt < 8; nt++)
#pragma unroll
        for (int r = 0; r < 4; r++)
          acc2[nt][r] = (float)(((double)acc2[nt][r] - sum[r]) * vs[r]) * gc[nt] + bec[nt];
    }

    // ---------------- writeback ----------------
#pragma unroll
    for (int r = 0; r < 4; r++) {
      int idx = r0 + w4 * 16 + (lg << 2) + r;
      if (idx >= p.nrows) continue;
      if constexpr (MODE == 0) {
        float* xr = p.xf + (size_t)idx * 128;
        unsigned short* xh_ = p.xhi_out + (size_t)idx * 128;
        unsigned short* xl_ = p.xlo_out + (size_t)idx * 128;
#pragma unroll
        for (int nt = 0; nt < 8; nt++) {
          int c = nt * 16 + l15; float v = acc2[nt][r];
          xr[c] = v;
          unsigned short hi = f2h(v);
          xh_[c] = hi; xl_[c] = loPart(v, hi);
        }
      } else if constexpr (MODE == 1) {
        float* er = p.ef + (size_t)idx * 128;
#pragma unroll
        for (int nt = 0; nt < 8; nt++) er[nt * 16 + l15] = acc2[nt][r];
      } else {  // MODE 3
        float* xr = p.xf + (size_t)idx * 128;
        unsigned short* xh_ = p.xhi_out + (size_t)idx * 128;
        unsigned short* xl_ = p.xlo_out + (size_t)idx * 128;
#pragma unroll
        for (int nt = 0; nt < 8; nt++) {
          int c = nt * 16 + l15;
          float v = acc2[nt][r] + xr[c];   // residual from f32 master
          xr[c] = v;
          unsigned short hi = f2h(v);
          xh_[c] = hi; xl_[c] = loPart(v, hi);
        }
      }
    }
  } else {
    // ---------------- decoder tail: out = h1 @ w2f + b2 (OUT=3, f64 acc) -----
    __syncthreads();   // tail reads h1 rows written by other waves
    if (tid < 192) {
      int row = tid / 3, oc = tid - row * 3;
      int n = r0 + row;
      if (n < p.nrows) {
        double s = (double)w2s[384 + oc];
        for (int k = 0; k < 128; k++) {
          int off = swz(row, k);
          double h = (double)h2f(HI(0)[off]) + (double)h2f(LO(0)[off]) * LO_INV_D;
          s += h * (double)w2s[k * 3 + oc];
        }
        p.out[(size_t)n * 3 + oc] = (float)s;
      }
    }
  }
}

extern "C" void kernel_launch(void* const* d_in, const int* in_sizes, int n_in,
                              void* d_out, int out_size, void* d_ws, size_t ws_size,
                              hipStream_t stream) {
  if (n_in < 31) return;
  const int N = in_sizes[0] / 15;
  const int E = in_sizes[1] / 7;
  const float* x        = (const float*)d_in[0];
  const float* ein      = (const float*)d_in[1];
  const int*   eidx     = (const int*)d_in[2];
  const float* enc_n_w1 = (const float*)d_in[3];
  const float* enc_n_b1 = (const float*)d_in[4];
  const float* enc_n_w2 = (const float*)d_in[5];
  const float* enc_n_b2 = (const float*)d_in[6];
  const float* enc_n_g  = (const float*)d_in[7];
  const float* enc_n_be = (const float*)d_in[8];
  const float* enc_e_w1 = (const float*)d_in[9];
  const float* enc_e_b1 = (const float*)d_in[10];
  const float* enc_e_w2 = (const float*)d_in[11];
  const float* enc_e_b2 = (const float*)d_in[12];
  const float* enc_e_g  = (const float*)d_in[13];
  const float* enc_e_be = (const float*)d_in[14];
  const float* pe_w1    = (const float*)d_in[15];
  const float* pe_b1    = (const float*)d_in[16];
  const float* pe_w2    = (const float*)d_in[17];
  const float* pe_b2    = (const float*)d_in[18];
  const float* pe_g     = (const float*)d_in[19];
  const float* pe_be    = (const float*)d_in[20];
  const float* pn_w1    = (const float*)d_in[21];
  const float* pn_b1    = (const float*)d_in[22];
  const float* pn_w2    = (const float*)d_in[23];
  const float* pn_b2    = (const float*)d_in[24];
  const float* pn_g     = (const float*)d_in[25];
  const float* pn_be    = (const float*)d_in[26];
  const float* dec_w1   = (const float*)d_in[27];
  const float* dec_b1   = (const float*)d_in[28];
  const float* dec_w2   = (const float*)d_in[29];
  const float* dec_b2   = (const float*)d_in[30];

  char* ws = (char*)d_ws;
  size_t off = 0;
  auto carve = [&](size_t bytes) -> void* {
    void* pp = ws + off; off += (bytes + 255) & ~(size_t)255; return pp;
  };
  float* xh            = (float*)carve((size_t)N * 128 * 4);
  unsigned short* xhi  = (unsigned short*)carve((size_t)N * 128 * 2);
  unsigned short* xlo  = (unsigned short*)carve((size_t)N * 128 * 2);
  float* eh            = (float*)carve((size_t)E * 128 * 4);
  int* aggi            = (int*)carve((size_t)N * 128 * 4);

  const int ktab[17] = {15, 128, 7, 128, 384, 384, 384, 128, 128, 128,
                        256, 256, 256, 128, 128, 128, 128};
  unsigned short* pk[17];
  for (int i = 0; i < 17; i++) {
    int kt = (ktab[i] + 31) / 32;
    pk[i] = (unsigned short*)carve((size_t)2 * kt * 8 * 512 * 2);  // hi+lo
  }
  if (off > ws_size) return;  // workspace too small -> fail validation loudly

  RepackParams rp;
  const float* wsrc[17] = {enc_n_w1, enc_n_w2, enc_e_w1, enc_e_w2,
                           pe_w1, pe_w1 + 384 * 128, pe_w1 + 2 * 384 * 128,
                           pe_w2, pe_w2 + 128 * 128, pe_w2 + 2 * 128 * 128,
                           pn_w1, pn_w1 + 256 * 128, pn_w1 + 2 * 256 * 128,
                           pn_w2, pn_w2 + 128 * 128, pn_w2 + 2 * 128 * 128,
                           dec_w1};
  for (int i = 0; i < 17; i++) {
    rp.it[i].src = wsrc[i]; rp.it[i].dst = pk[i];
    rp.it[i].K = ktab[i]; rp.it[i].Kt = (ktab[i] + 31) / 32;
  }
  repack_kernel<<<dim3(96, 17), 256, 0, stream>>>(rp);

  auto wlo = [&](int i) { return pk[i] + (size_t)((ktab[i] + 31) / 32) * 8 * 512; };
  const int gN = (N + 63) / 64, gE = (E + 63) / 64, gE96 = (E + 95) / 96;

  {  // node encoder
    KParams kp{};
    kp.w1h = pk[0]; kp.w1l = wlo(0); kp.w2h = pk[1]; kp.w2l = wlo(1);
    kp.b1 = enc_n_b1; kp.b2 = enc_n_b2; kp.g = enc_n_g; kp.be = enc_n_be;
    kp.srcA = x; kp.xf = xh; kp.xhi_out = xhi; kp.xlo_out = xlo;
    kp.nrows = N; kp.kin = 15;
    gnn_kernel<0><<<gN, 256, 0, stream>>>(kp);
  }
  {  // edge encoder
    KParams kp{};
    kp.w1h = pk[2]; kp.w1l = wlo(2); kp.w2h = pk[3]; kp.w2l = wlo(3);
    kp.b1 = enc_e_b1; kp.b2 = enc_e_b2; kp.g = enc_e_g; kp.be = enc_e_be;
    kp.srcA = ein; kp.ef = eh; kp.nrows = E; kp.kin = 7;
    gnn_kernel<1><<<gE, 256, 0, stream>>>(kp);
  }
  for (int i = 0; i < 3; i++) {
    hipMemsetAsync(aggi, 0, (size_t)N * 128 * 4, stream);
    {  // edge processor (768 threads: 6 msg waves + 6 edge-update waves)
      KParams kp{};
      kp.w1h = pk[4 + i]; kp.w1l = wlo(4 + i);
      kp.w2h = pk[7 + i]; kp.w2l = wlo(7 + i);
      kp.b1 = pe_b1 + i * 128; kp.b2 = pe_b2 + i * 128;
      kp.g = pe_g + i * 128; kp.be = pe_be + i * 128;
      kp.xhi = xhi; kp.xlo = xlo; kp.ef = eh;
      kp.rowi = eidx; kp.coli = eidx + E;
      kp.aggi = aggi; kp.nrows = E;
      edge_kernel<<<gE96, 768, 0, stream>>>(kp);
    }
    {  // node processor (reads deterministic int32 aggregate via double)
      KParams kp{};
      kp.w1h = pk[10 + i]; kp.w1l = wlo(10 + i);
      kp.w2h = pk[13 + i]; kp.w2l = wlo(13 + i);
      kp.b1 = pn_b1 + i * 128; kp.b2 = pn_b2 + i * 128;
      kp.g = pn_g + i * 128; kp.be = pn_be + i * 128;
      kp.aggi = aggi; kp.xhi = xhi; kp.xlo = xlo;
      kp.xf = xh; kp.xhi_out = xhi; kp.xlo_out = xlo; kp.nrows = N;
      gnn_kernel<3><<<gN, 256, 0, stream>>>(kp);
    }
  }
  {  // decoder
    KParams kp{};
    kp.w1h = pk[16]; kp.w1l = wlo(16); kp.b1 = dec_b1;
    kp.xhi = xhi; kp.xlo = xlo; kp.w2f = dec_w2; kp.b2f = dec_b2;
    kp.out = (float*)d_out; kp.nrows = N;
    gnn_kernel<4><<<gN, 256, 0, stream>>>(kp);
  }
}

// Round 22
// 1805.213 us; speedup vs baseline: 1.2012x; 1.0439x over previous
//
#include <hip/hip_runtime.h>
#include <stdint.h>
#include <math.h>

#define DEVI __device__ __forceinline__

typedef __attribute__((ext_vector_type(8))) _Float16 f16x8;
typedef __attribute__((ext_vector_type(4))) float f32x4;

#define LO_SCALE 2048.0f
#define LO_INV (1.0f / 2048.0f)
#define LO_INV_D (1.0 / 2048.0)
// int32 fixed-point aggregation at 2^22, quantized/read back through double:
// per-message error <= 1.2e-7 absolute; integer sum is order-exact.
#define AGG_SCALE_D 4194304.0
#define AGG_INV_D (1.0 / 4194304.0)

DEVI unsigned short f2h(float f) {
  union { _Float16 h; unsigned short u; } v; v.h = (_Float16)f; return v.u;
}
DEVI float h2f(unsigned short u) {
  union { unsigned short u; _Float16 h; } v; v.u = u; return (float)v.h;
}
DEVI unsigned short loPart(float v, unsigned short hi) {
  return f2h((v - h2f(hi)) * LO_SCALE);
}
DEVI f32x4 mfma16(f16x8 a, f16x8 b, f32x4 c) {
  return __builtin_amdgcn_mfma_f32_16x16x32_f16(a, b, c, 0, 0, 0);
}
// Full 4-term pair product: acc += Ah*Bh ; accx += Ah*Bl + Al*Bh ; accy += Al*Bl
// (accx scaled x2048, accy x2048^2). Combine in f64: ~f32-exact GEMM.
DEVI void mfma4(f16x8 ah, f16x8 al, f16x8 bh, f16x8 bl,
                f32x4& acc, f32x4& accx, f32x4& accy) {
  acc  = mfma16(ah, bh, acc);
  accx = mfma16(ah, bl, accx);
  accx = mfma16(al, bh, accx);
  accy = mfma16(al, bl, accy);
}
DEVI float combine3(float a, float ax, float ay, float b) {
  return (float)((double)a + ((double)ax + (double)ay * LO_INV_D) * LO_INV_D + (double)b);
}
// swizzled element offset inside one [rows][128] fp16 tile (row stride 256B).
DEVI int swz(int row, int col) { return row * 128 + (col ^ ((row & 7) << 3)); }

struct KParams {
  const unsigned short* w1h; const unsigned short* w1l;
  const unsigned short* w2h; const unsigned short* w2l;
  const float* b1; const float* b2; const float* g; const float* be;
  const float* srcA;                 // ENC: x/e
  const unsigned short* xhi;         // fp16 hi mirror of xh
  const unsigned short* xlo;         // fp16 lo mirror (x2048)
  float* xf;                         // xh f32 master
  float* ef;                         // eh f32 master
  unsigned short* xhi_out; unsigned short* xlo_out;
  const int* rowi; const int* coli;
  int* aggi;                         // [N,128] int32 2^22 fixed-point aggregate
  float* out;
  const float* w2f; const float* b2f;  // decoder layer-2 (f32)
  int nrows; int kin;
};

struct RepackItem { const float* src; unsigned short* dst; int K; int Kt; };
struct RepackParams { RepackItem it[17]; };

// Pack W [K][128] f32 -> fp16 hi/lo MFMA B-fragments. hi at [0, Kt*8*512),
// lo (x2048) at [Kt*8*512, 2*Kt*8*512).
__global__ __launch_bounds__(256) void repack_kernel(RepackParams rp) {
  const RepackItem w = rp.it[blockIdx.y];
  const int f = blockIdx.x;
  if (f >= w.Kt * 8) return;
  const int kt = f >> 3, nt = f & 7;
  const size_t loOff = (size_t)w.Kt * 8 * 512;
  for (int s = threadIdx.x; s < 512; s += 256) {
    int ln = s >> 3, j = s & 7;
    int k = kt * 32 + ((ln >> 4) << 3) + j;
    int c = nt * 16 + (ln & 15);
    float v = (k < w.K) ? w.src[(size_t)k * 128 + c] : 0.f;
    unsigned short hi = f2h(v);
    w.dst[(size_t)f * 512 + s] = hi;
    w.dst[loOff + (size_t)f * 512 + s] = loPart(v, hi);
  }
}

// ---------------- edge processor (BK=64 staging: half the barriers) ----------
// 768 threads (12 waves) over 96 edges; waves 0-5 = msg variant (bands 0-5),
// waves 6-11 = edge-update. Weights staged as PAIRS of 16KB K-steps into a
// 2 x 32KB LDS double-buffer: one stage + one barrier covers TWO K-steps,
// halving the vmcnt(0)+s_barrier drains (16 -> 9) that dominate the stall.
// LDS = h1 hi/lo (96KB) + wbuf (64KB) = 160KB = full gfx950 pool (1 block/CU,
// 3 waves/SIMD — unchanged). Weight bits and MFMA order identical to R21 ->
// output bit-identical (absmax 0.0078125).
__global__ __attribute__((amdgpu_flat_work_group_size(768, 768)))
void edge_kernel(KParams p) {
  constexpr int NT = 768;
  constexpr int REG = 12288;                       // elems per hi (or lo) region
  __shared__ __align__(16) unsigned short stA[2 * 2 * REG];   // h1 hi/lo x 2 variants
  __shared__ __align__(16) unsigned short wbuf[2 * 16384];    // 2 bufs x (2 steps x 8K)

  const int tid = threadIdx.x;
  const int lane = tid & 63;
  const int wave = tid >> 6;
  const int w4 = wave % 6;        // 16-row band index
  const int vrt = wave / 6;       // variant: 0=msg 1=edge-update
  const int r0 = blockIdx.x * 96;
  const int l15 = lane & 15;
  const int lg = lane >> 4;

  auto HI = [&](int t) { return stA + 2 * t * REG; };
  auto LO = [&](int t) { return stA + 2 * t * REG + REG; };

  // stage steps {2*pair, 2*pair+1} (2 x 8192 elems) into wbuf[buf]
  auto stageW2 = [&](int pair, int buf) {
    for (int i = tid; i < 2048; i += NT) {
      const int sub = i >> 10;              // which step of the pair
      const int s = pair * 2 + sub;
      const int j = i & 1023;               // 0..511 hi, 512..1023 lo
      const unsigned short* h = (s < 12) ? p.w1h + s * 4096 : p.w2h + (s - 12) * 4096;
      const unsigned short* l = (s < 12) ? p.w1l + s * 4096 : p.w2l + (s - 12) * 4096;
      *(f16x8*)&wbuf[buf * 16384 + sub * 8192 +
                     ((j < 512) ? j * 8 : 4096 + (j - 512) * 8)] =
          *(const f16x8*)((j < 512) ? h + j * 8 : l + (j - 512) * 8);
    }
  };

  stageW2(0, 0);   // steps 0,1
  __syncthreads();

  // ---------------- layer 1 (K = 12*32, 6 step-pairs) ----------------
  const f32x4 zz = {0.f, 0.f, 0.f, 0.f};
  f32x4 acc1[8], acc1x[8], acc1y[8];
#pragma unroll
  for (int nt = 0; nt < 8; nt++) { acc1[nt] = zz; acc1x[nt] = zz; acc1y[nt] = zz; }
  const int arow = w4 * 16 + l15;
  const int acol = lg << 3;

  const int ridx = r0 + arow;
  const int ec = (ridx < p.nrows) ? ridx : 0;   // clamped (outputs discarded)
  const int nc = p.coli[ec], nr = p.rowi[ec];
  // msg variant: [Xc, Xr, Ee] ; edge-update variant: [Xr, Xc, Ee]
  const unsigned short* aH = p.xhi + (size_t)(vrt ? nr : nc) * 128;
  const unsigned short* aL = p.xlo + (size_t)(vrt ? nr : nc) * 128;
  const unsigned short* bH = p.xhi + (size_t)(vrt ? nc : nr) * 128;
  const unsigned short* bL = p.xlo + (size_t)(vrt ? nc : nr) * 128;
  const float* ep = p.ef + (size_t)ec * 128;
#pragma unroll
  for (int pr = 0; pr < 6; pr++) {
    const int cur = pr & 1;
    stageW2(pr + 1, cur ^ 1);   // pairs 1..6 (pair 6 = W2 steps 12,13)
#pragma unroll
    for (int half = 0; half < 2; half++) {
      const int kt = pr * 2 + half;
      const int kc = (kt & 3) * 32 + acol;
      f16x8 ah, al;
      if (kt < 4)      { ah = *(const f16x8*)(aH + kc); al = *(const f16x8*)(aL + kc); }
      else if (kt < 8) { ah = *(const f16x8*)(bH + kc); al = *(const f16x8*)(bL + kc); }
      else {
        union { unsigned short u[8]; f16x8 v; } th, tl;
#pragma unroll
        for (int j = 0; j < 8; j++) {
          float v = ep[kc + j];
          th.u[j] = f2h(v); tl.u[j] = loPart(v, th.u[j]);
        }
        ah = th.v; al = tl.v;
      }
#pragma unroll
      for (int nt = 0; nt < 8; nt++) {
        f16x8 bh = *(const f16x8*)&wbuf[cur * 16384 + half * 8192 + nt * 512 + lane * 8];
        f16x8 bl = *(const f16x8*)&wbuf[cur * 16384 + half * 8192 + 4096 + nt * 512 + lane * 8];
        mfma4(ah, al, bh, bl, acc1[nt], acc1x[nt], acc1y[nt]);
      }
    }
    __syncthreads();
  }

  // ---------------- h1 = relu(acc + b1) -> LDS hi/lo (region vrt) ----------
  // Each wave writes/reads only its own 16-row band (in-order per wave).
  float b1c[8];
#pragma unroll
  for (int nt = 0; nt < 8; nt++) b1c[nt] = p.b1[nt * 16 + l15];
#pragma unroll
  for (int nt = 0; nt < 8; nt++) {
#pragma unroll
    for (int r = 0; r < 4; r++) {
      int row = w4 * 16 + (lg << 2) + r;
      int col = nt * 16 + l15;
      int off = swz(row, col);
      float v = combine3(acc1[nt][r], acc1x[nt][r], acc1y[nt][r], b1c[nt]);
      v = v > 0.f ? v : 0.f;
      unsigned short hi = f2h(v);
      HI(vrt)[off] = hi; LO(vrt)[off] = loPart(v, hi);
    }
  }

  // ---------------- layer 2 (K=128, 2 step-pairs; pair 6 = buf0) ----------
  f32x4 acc2[8], acc2x[8], acc2y[8];
#pragma unroll
  for (int nt = 0; nt < 8; nt++) { acc2[nt] = zz; acc2x[nt] = zz; acc2y[nt] = zz; }
#pragma unroll
  for (int pr = 6; pr < 8; pr++) {
    const int cur = pr & 1;
    if (pr == 6) stageW2(7, 1);   // W2 steps 14,15 -> buf1
#pragma unroll
    for (int half = 0; half < 2; half++) {
      const int kt2 = (pr - 6) * 2 + half;   // 0..3
      int so = swz(arow, kt2 * 32 + acol);
      f16x8 ah = *(const f16x8*)&HI(vrt)[so];
      f16x8 al = *(const f16x8*)&LO(vrt)[so];
#pragma unroll
      for (int nt = 0; nt < 8; nt++) {
        f16x8 bh = *(const f16x8*)&wbuf[cur * 16384 + half * 8192 + nt * 512 + lane * 8];
        f16x8 bl = *(const f16x8*)&wbuf[cur * 16384 + half * 8192 + 4096 + nt * 512 + lane * 8];
        mfma4(ah, al, bh, bl, acc2[nt], acc2x[nt], acc2y[nt]);
      }
    }
    if (pr == 6) __syncthreads();
  }

  // ---------------- LayerNorm epilogue (f64 statistics) ----------------
  float b2c[8], gc[8], bec[8];
#pragma unroll
  for (int nt = 0; nt < 8; nt++) {
    int c = nt * 16 + l15;
    b2c[nt] = p.b2[c]; gc[nt] = p.g[c]; bec[nt] = p.be[c];
  }
  {
    double sum[4] = {0.0, 0.0, 0.0, 0.0};
#pragma unroll
    for (int nt = 0; nt < 8; nt++)
#pragma unroll
      for (int r = 0; r < 4; r++) {
        acc2[nt][r] = combine3(acc2[nt][r], acc2x[nt][r], acc2y[nt][r], b2c[nt]);
        sum[r] += (double)acc2[nt][r];
      }
#pragma unroll
    for (int r = 0; r < 4; r++) {
#pragma unroll
      for (int m = 1; m < 16; m <<= 1) sum[r] += __shfl_xor(sum[r], m);
      sum[r] *= (1.0 / 128.0);
    }
    double vs[4] = {0.0, 0.0, 0.0, 0.0};
#pragma unroll
    for (int nt = 0; nt < 8; nt++)
#pragma unroll
      for (int r = 0; r < 4; r++) {
        double d = (double)acc2[nt][r] - sum[r];
        vs[r] += d * d;
      }
#pragma unroll
    for (int r = 0; r < 4; r++) {
#pragma unroll
      for (int m = 1; m < 16; m <<= 1) vs[r] += __shfl_xor(vs[r], m);
      vs[r] = 1.0 / sqrt(vs[r] * (1.0 / 128.0) + 1e-5);
    }
#pragma unroll
    for (int nt = 0; nt < 8; nt++)
#pragma unroll
      for (int r = 0; r < 4; r++)
        acc2[nt][r] = (float)(((double)acc2[nt][r] - sum[r]) * vs[r]) * gc[nt] + bec[nt];
  }

  // order all ef reads (layer 1) before variant-1's in-place ef writes below.
  __syncthreads();

  // ---------------- writeback ----------------
#pragma unroll
  for (int r = 0; r < 4; r++) {
    int idx = r0 + w4 * 16 + (lg << 2) + r;
    if (idx >= p.nrows) continue;
    if (vrt == 0) {
      int tgt = p.coli[idx];
      int* ar = p.aggi + (size_t)tgt * 128;
#pragma unroll
      for (int nt = 0; nt < 8; nt++) {
        int q = __double2int_rn((double)acc2[nt][r] * AGG_SCALE_D);
        atomicAdd(&ar[nt * 16 + l15], q);
      }
    } else {
      float* er = p.ef + (size_t)idx * 128;
#pragma unroll
      for (int nt = 0; nt < 8; nt++) {
        int c = nt * 16 + l15;
        er[c] = acc2[nt][r] + er[c];
      }
    }
  }
}

// Modes: 0=node-encoder 1=edge-encoder 3=node-processor 4=decoder
template <int MODE>
__global__ __launch_bounds__(256, 2)
void gnn_kernel(KParams p) {
  constexpr int NT = 256;
  constexpr int REG = 8192;                        // elems per hi (or lo) region
  constexpr int NREG = (MODE == 3) ? 2 : 1;
  __shared__ __align__(16) unsigned short stA[NREG * 2 * REG];
  __shared__ float w2s[(MODE == 4) ? 392 : 1];

  const int tid = threadIdx.x;
  const int lane = tid & 63;
  const int wave = tid >> 6;
  const int w4 = wave;            // 16-row band index
  const int r0 = blockIdx.x * 64;
  const int l15 = lane & 15;
  const int lg = lane >> 4;

  auto HI = [&](int t) { return stA + 2 * t * REG; };
  auto LO = [&](int t) { return stA + 2 * t * REG + REG; };

  // ---------------- stage inputs (fp16 hi/lo, swizzled) ----------------
  if constexpr (MODE == 3) {
    for (int s = tid; s < 1024; s += NT) {
      int row = s >> 4, cc = (s & 15) * 8;
      int n = r0 + row;
      int off = swz(row, cc);
      if (n < p.nrows) {
        const int* ap = p.aggi + (size_t)n * 128 + cc;
        union { unsigned short u[8]; f16x8 v; } th, tl;
#pragma unroll
        for (int j = 0; j < 8; j++) {
          float v = (float)((double)ap[j] * AGG_INV_D);   // exact int->double->f32
          th.u[j] = f2h(v); tl.u[j] = loPart(v, th.u[j]);
        }
        *(f16x8*)&HI(0)[off] = th.v; *(f16x8*)&LO(0)[off] = tl.v;
        *(f16x8*)&HI(1)[off] = *(const f16x8*)(p.xhi + (size_t)n * 128 + cc);
        *(f16x8*)&LO(1)[off] = *(const f16x8*)(p.xlo + (size_t)n * 128 + cc);
      } else {
        f16x8 z = {0,0,0,0,0,0,0,0};
        *(f16x8*)&HI(0)[off] = z; *(f16x8*)&LO(0)[off] = z;
        *(f16x8*)&HI(1)[off] = z; *(f16x8*)&LO(1)[off] = z;
      }
    }
  } else if constexpr (MODE == 0 || MODE == 1) {
    for (int s = tid; s < 256; s += NT) {
      int row = s >> 2, cc = (s & 3) * 8;
      int n = r0 + row;
      union { unsigned short u[8]; f16x8 v; } th, tl;
#pragma unroll
      for (int j = 0; j < 8; j++) {
        int k = cc + j;
        float v = (n < p.nrows && k < p.kin) ? p.srcA[(size_t)n * p.kin + k] : 0.f;
        th.u[j] = f2h(v); tl.u[j] = loPart(v, th.u[j]);
      }
      int off = swz(row, cc);
      *(f16x8*)&HI(0)[off] = th.v; *(f16x8*)&LO(0)[off] = tl.v;
    }
  } else if constexpr (MODE == 4) {
    for (int s = tid; s < 1024; s += NT) {
      int row = s >> 4, cc = (s & 15) * 8;
      int n = r0 + row;
      int off = swz(row, cc);
      f16x8 z = {0,0,0,0,0,0,0,0};
      if (n < p.nrows) {
        *(f16x8*)&HI(0)[off] = *(const f16x8*)(p.xhi + (size_t)n * 128 + cc);
        *(f16x8*)&LO(0)[off] = *(const f16x8*)(p.xlo + (size_t)n * 128 + cc);
      } else { *(f16x8*)&HI(0)[off] = z; *(f16x8*)&LO(0)[off] = z; }
    }
    for (int s = tid; s < 387; s += NT) w2s[s] = (s < 384) ? p.w2f[s] : p.b2f[s - 384];
  }
  __syncthreads();

  // ---------------- layer 1 (K = K1T*32) ----------------
  constexpr int K1T = (MODE == 3) ? 8 : (MODE == 4) ? 4 : 1;
  const f32x4 zz = {0.f, 0.f, 0.f, 0.f};
  f32x4 acc1[8], acc1x[8], acc1y[8];
#pragma unroll
  for (int nt = 0; nt < 8; nt++) { acc1[nt] = zz; acc1x[nt] = zz; acc1y[nt] = zz; }
  const int arow = w4 * 16 + l15;
  const int acol = lg << 3;

#pragma unroll
  for (int kt = 0; kt < K1T; kt++) {
    int t = kt >> 2;
    int so = swz(arow, (kt & 3) * 32 + acol);
    f16x8 ah = *(const f16x8*)&HI(t)[so];
    f16x8 al = *(const f16x8*)&LO(t)[so];
#pragma unroll
    for (int nt = 0; nt < 8; nt++) {
      f16x8 bh = *(const f16x8*)&p.w1h[(size_t)(kt * 8 + nt) * 512 + lane * 8];
      f16x8 bl = *(const f16x8*)&p.w1l[(size_t)(kt * 8 + nt) * 512 + lane * 8];
      mfma4(ah, al, bh, bl, acc1[nt], acc1x[nt], acc1y[nt]);
    }
  }

  // ---------------- h1 = relu(acc + b1) -> LDS hi/lo (region 0) ----------
  float b1c[8];
#pragma unroll
  for (int nt = 0; nt < 8; nt++) b1c[nt] = p.b1[nt * 16 + l15];
#pragma unroll
  for (int nt = 0; nt < 8; nt++) {
#pragma unroll
    for (int r = 0; r < 4; r++) {
      int row = w4 * 16 + (lg << 2) + r;
      int col = nt * 16 + l15;
      int off = swz(row, col);
      float v = combine3(acc1[nt][r], acc1x[nt][r], acc1y[nt][r], b1c[nt]);
      v = v > 0.f ? v : 0.f;
      unsigned short hi = f2h(v);
      HI(0)[off] = hi; LO(0)[off] = loPart(v, hi);
    }
  }

  if constexpr (MODE != 4) {
    // ---------------- layer 2 (K=128 from h1 in LDS) ----------------
    f32x4 acc2[8], acc2x[8], acc2y[8];
#pragma unroll
    for (int nt = 0; nt < 8; nt++) { acc2[nt] = zz; acc2x[nt] = zz; acc2y[nt] = zz; }
#pragma unroll
    for (int kt = 0; kt < 4; kt++) {
      int so = swz(arow, kt * 32 + acol);
      f16x8 ah = *(const f16x8*)&HI(0)[so];
      f16x8 al = *(const f16x8*)&LO(0)[so];
#pragma unroll
      for (int nt = 0; nt < 8; nt++) {
        f16x8 bh = *(const f16x8*)&p.w2h[(size_t)(kt * 8 + nt) * 512 + lane * 8];
        f16x8 bl = *(const f16x8*)&p.w2l[(size_t)(kt * 8 + nt) * 512 + lane * 8];
        mfma4(ah, al, bh, bl, acc2[nt], acc2x[nt], acc2y[nt]);
      }
    }

    // ---------------- LayerNorm epilogue (f64 statistics) ----------------
    float b2c[8], gc[8], bec[8];
#pragma unroll
    for (int nt = 0; nt < 8; nt++) {
      int c = nt * 16 + l15;
      b2c[nt] = p.b2[c]; gc[nt] = p.g[c]; bec[nt] = p.be[c];
    }
    {
      double sum[4] = {0.0, 0.0, 0.0, 0.0};
#pragma unroll
      for (int nt = 0; nt < 8; nt++)
#pragma unroll
        for (int r = 0; r < 4; r++) {
          acc2[nt][r] = combine3(acc2[nt][r], acc2x[nt][r], acc2y[nt][r], b2c[nt]);
          sum[r] += (double)acc2[nt][r];
        }
#pragma unroll
      for (int r = 0; r < 4; r++) {
#pragma unroll
        for (int m = 1; m < 16; m <<= 1) sum[r] += __shfl_xor(sum[r], m);
        sum[r] *= (1.0 / 128.0);
      }
      double vs[4] = {0.0, 0.0, 0.0, 0.0};
#pragma unroll
      for (int nt = 0; nt < 8; nt++)
#pragma unroll
        for (int r = 0; r < 4; r++) {
          double d = (double)acc2[nt][r] - sum[r];
          vs[r] += d * d;
        }
#pragma unroll
      for (int r = 0; r < 4; r++) {
#pragma unroll
        for (int m = 1; m < 16; m <<= 1) vs[r] += __shfl_xor(vs[r], m);
        vs[r] = 1.0 / sqrt(vs[r] * (1.0 / 128.0) + 1e-5);
      }
#pragma unroll
      for (int nt = 0; nt < 8; nt++)
#pragma unroll
        for (int r = 0; r < 4; r++)
          acc2[nt][r] = (float)(((double)acc2[nt][r] - sum[r]) * vs[r]) * gc[nt] + bec[nt];
    }

    // ---------------- writeback ----------------
#pragma unroll
    for (int r = 0; r < 4; r++) {
      int idx = r0 + w4 * 16 + (lg << 2) + r;
      if (idx >= p.nrows) continue;
      if constexpr (MODE == 0) {
        float* xr = p.xf + (size_t)idx * 128;
        unsigned short* xh_ = p.xhi_out + (size_t)idx * 128;
        unsigned short* xl_ = p.xlo_out + (size_t)idx * 128;
#pragma unroll
        for (int nt = 0; nt < 8; nt++) {
          int c = nt * 16 + l15; float v = acc2[nt][r];
          xr[c] = v;
          unsigned short hi = f2h(v);
          xh_[c] = hi; xl_[c] = loPart(v, hi);
        }
      } else if constexpr (MODE == 1) {
        float* er = p.ef + (size_t)idx * 128;
#pragma unroll
        for (int nt = 0; nt < 8; nt++) er[nt * 16 + l15] = acc2[nt][r];
      } else {  // MODE 3
        float* xr = p.xf + (size_t)idx * 128;
        unsigned short* xh_ = p.xhi_out + (size_t)idx * 128;
        unsigned short* xl_ = p.xlo_out + (size_t)idx * 128;
#pragma unroll
        for (int nt = 0; nt < 8; nt++) {
          int c = nt * 16 + l15;
          float v = acc2[nt][r] + xr[c];   // residual from f32 master
          xr[c] = v;
          unsigned short hi = f2h(v);
          xh_[c] = hi; xl_[c] = loPart(v, hi);
        }
      }
    }
  } else {
    // ---------------- decoder tail: out = h1 @ w2f + b2 (OUT=3, f64 acc) -----
    __syncthreads();   // tail reads h1 rows written by other waves
    if (tid < 192) {
      int row = tid / 3, oc = tid - row * 3;
      int n = r0 + row;
      if (n < p.nrows) {
        double s = (double)w2s[384 + oc];
        for (int k = 0; k < 128; k++) {
          int off = swz(row, k);
          double h = (double)h2f(HI(0)[off]) + (double)h2f(LO(0)[off]) * LO_INV_D;
          s += h * (double)w2s[k * 3 + oc];
        }
        p.out[(size_t)n * 3 + oc] = (float)s;
      }
    }
  }
}

extern "C" void kernel_launch(void* const* d_in, const int* in_sizes, int n_in,
                              void* d_out, int out_size, void* d_ws, size_t ws_size,
                              hipStream_t stream) {
  if (n_in < 31) return;
  const int N = in_sizes[0] / 15;
  const int E = in_sizes[1] / 7;
  const float* x        = (const float*)d_in[0];
  const float* ein      = (const float*)d_in[1];
  const int*   eidx     = (const int*)d_in[2];
  const float* enc_n_w1 = (const float*)d_in[3];
  const float* enc_n_b1 = (const float*)d_in[4];
  const float* enc_n_w2 = (const float*)d_in[5];
  const float* enc_n_b2 = (const float*)d_in[6];
  const float* enc_n_g  = (const float*)d_in[7];
  const float* enc_n_be = (const float*)d_in[8];
  const float* enc_e_w1 = (const float*)d_in[9];
  const float* enc_e_b1 = (const float*)d_in[10];
  const float* enc_e_w2 = (const float*)d_in[11];
  const float* enc_e_b2 = (const float*)d_in[12];
  const float* enc_e_g  = (const float*)d_in[13];
  const float* enc_e_be = (const float*)d_in[14];
  const float* pe_w1    = (const float*)d_in[15];
  const float* pe_b1    = (const float*)d_in[16];
  const float* pe_w2    = (const float*)d_in[17];
  const float* pe_b2    = (const float*)d_in[18];
  const float* pe_g     = (const float*)d_in[19];
  const float* pe_be    = (const float*)d_in[20];
  const float* pn_w1    = (const float*)d_in[21];
  const float* pn_b1    = (const float*)d_in[22];
  const float* pn_w2    = (const float*)d_in[23];
  const float* pn_b2    = (const float*)d_in[24];
  const float* pn_g     = (const float*)d_in[25];
  const float* pn_be    = (const float*)d_in[26];
  const float* dec_w1   = (const float*)d_in[27];
  const float* dec_b1   = (const float*)d_in[28];
  const float* dec_w2   = (const float*)d_in[29];
  const float* dec_b2   = (const float*)d_in[30];

  char* ws = (char*)d_ws;
  size_t off = 0;
  auto carve = [&](size_t bytes) -> void* {
    void* pp = ws + off; off += (bytes + 255) & ~(size_t)255; return pp;
  };
  float* xh            = (float*)carve((size_t)N * 128 * 4);
  unsigned short* xhi  = (unsigned short*)carve((size_t)N * 128 * 2);
  unsigned short* xlo  = (unsigned short*)carve((size_t)N * 128 * 2);
  float* eh            = (float*)carve((size_t)E * 128 * 4);
  int* aggi            = (int*)carve((size_t)N * 128 * 4);

  const int ktab[17] = {15, 128, 7, 128, 384, 384, 384, 128, 128, 128,
                        256, 256, 256, 128, 128, 128, 128};
  unsigned short* pk[17];
  for (int i = 0; i < 17; i++) {
    int kt = (ktab[i] + 31) / 32;
    pk[i] = (unsigned short*)carve((size_t)2 * kt * 8 * 512 * 2);  // hi+lo
  }
  if (off > ws_size) return;  // workspace too small -> fail validation loudly

  RepackParams rp;
  const float* wsrc[17] = {enc_n_w1, enc_n_w2, enc_e_w1, enc_e_w2,
                           pe_w1, pe_w1 + 384 * 128, pe_w1 + 2 * 384 * 128,
                           pe_w2, pe_w2 + 128 * 128, pe_w2 + 2 * 128 * 128,
                           pn_w1, pn_w1 + 256 * 128, pn_w1 + 2 * 256 * 128,
                           pn_w2, pn_w2 + 128 * 128, pn_w2 + 2 * 128 * 128,
                           dec_w1};
  for (int i = 0; i < 17; i++) {
    rp.it[i].src = wsrc[i]; rp.it[i].dst = pk[i];
    rp.it[i].K = ktab[i]; rp.it[i].Kt = (ktab[i] + 31) / 32;
  }
  repack_kernel<<<dim3(96, 17), 256, 0, stream>>>(rp);

  auto wlo = [&](int i) { return pk[i] + (size_t)((ktab[i] + 31) / 32) * 8 * 512; };
  const int gN = (N + 63) / 64, gE = (E + 63) / 64, gE96 = (E + 95) / 96;

  {  // node encoder
    KParams kp{};
    kp.w1h = pk[0]; kp.w1l = wlo(0); kp.w2h = pk[1]; kp.w2l = wlo(1);
    kp.b1 = enc_n_b1; kp.b2 = enc_n_b2; kp.g = enc_n_g; kp.be = enc_n_be;
    kp.srcA = x; kp.xf = xh; kp.xhi_out = xhi; kp.xlo_out = xlo;
    kp.nrows = N; kp.kin = 15;
    gnn_kernel<0><<<gN, 256, 0, stream>>>(kp);
  }
  {  // edge encoder
    KParams kp{};
    kp.w1h = pk[2]; kp.w1l = wlo(2); kp.w2h = pk[3]; kp.w2l = wlo(3);
    kp.b1 = enc_e_b1; kp.b2 = enc_e_b2; kp.g = enc_e_g; kp.be = enc_e_be;
    kp.srcA = ein; kp.ef = eh; kp.nrows = E; kp.kin = 7;
    gnn_kernel<1><<<gE, 256, 0, stream>>>(kp);
  }
  for (int i = 0; i < 3; i++) {
    hipMemsetAsync(aggi, 0, (size_t)N * 128 * 4, stream);
    {  // edge processor (768 threads: 6 msg waves + 6 edge-update waves)
      KParams kp{};
      kp.w1h = pk[4 + i]; kp.w1l = wlo(4 + i);
      kp.w2h = pk[7 + i]; kp.w2l = wlo(7 + i);
      kp.b1 = pe_b1 + i * 128; kp.b2 = pe_b2 + i * 128;
      kp.g = pe_g + i * 128; kp.be = pe_be + i * 128;
      kp.xhi = xhi; kp.xlo = xlo; kp.ef = eh;
      kp.rowi = eidx; kp.coli = eidx + E;
      kp.aggi = aggi; kp.nrows = E;
      edge_kernel<<<gE96, 768, 0, stream>>>(kp);
    }
    {  // node processor (reads deterministic int32 aggregate via double)
      KParams kp{};
      kp.w1h = pk[10 + i]; kp.w1l = wlo(10 + i);
      kp.w2h = pk[13 + i]; kp.w2l = wlo(13 + i);
      kp.b1 = pn_b1 + i * 128; kp.b2 = pn_b2 + i * 128;
      kp.g = pn_g + i * 128; kp.be = pn_be + i * 128;
      kp.aggi = aggi; kp.xhi = xhi; kp.xlo = xlo;
      kp.xf = xh; kp.xhi_out = xhi; kp.xlo_out = xlo; kp.nrows = N;
      gnn_kernel<3><<<gN, 256, 0, stream>>>(kp);
    }
  }
  {  // decoder
    KParams kp{};
    kp.w1h = pk[16]; kp.w1l = wlo(16); kp.b1 = dec_b1;
    kp.xhi = xhi; kp.xlo = xlo; kp.w2f = dec_w2; kp.b2f = dec_b2;
    kp.out = (float*)d_out; kp.nrows = N;
    gnn_kernel<4><<<gN, 256, 0, stream>>>(kp);
  }
}

// Round 23
// 1662.455 us; speedup vs baseline: 1.3044x; 1.0859x over previous
//
#include <hip/hip_runtime.h>
#include <stdint.h>
#include <math.h>

#define DEVI __device__ __forceinline__

typedef __attribute__((ext_vector_type(8))) _Float16 f16x8;
typedef __attribute__((ext_vector_type(4))) float f32x4;

#define LO_SCALE 2048.0f
#define LO_INV (1.0f / 2048.0f)
#define LO_INV_D (1.0 / 2048.0)
// int32 fixed-point aggregation at 2^22, quantized/read back through double:
// per-message error <= 1.2e-7 absolute; integer sum is order-exact.
#define AGG_SCALE_D 4194304.0
#define AGG_INV_D (1.0 / 4194304.0)

DEVI unsigned short f2h(float f) {
  union { _Float16 h; unsigned short u; } v; v.h = (_Float16)f; return v.u;
}
DEVI float h2f(unsigned short u) {
  union { unsigned short u; _Float16 h; } v; v.u = u; return (float)v.h;
}
DEVI unsigned short loPart(float v, unsigned short hi) {
  return f2h((v - h2f(hi)) * LO_SCALE);
}
DEVI f32x4 mfma16(f16x8 a, f16x8 b, f32x4 c) {
  return __builtin_amdgcn_mfma_f32_16x16x32_f16(a, b, c, 0, 0, 0);
}
// 4-term pair product (node/encoder paths): acc += Ah*Bh; accx += Ah*Bl + Al*Bh;
// accy += Al*Bl.  Combine in f64: ~f32-exact GEMM.
DEVI void mfma4(f16x8 ah, f16x8 al, f16x8 bh, f16x8 bl,
                f32x4& acc, f32x4& accx, f32x4& accy) {
  acc  = mfma16(ah, bh, acc);
  accx = mfma16(ah, bl, accx);
  accx = mfma16(al, bh, accx);
  accy = mfma16(al, bl, accy);
}
// 3-term pair product (edge path): drops Al*Bl (~2^-22 relative) — 25% fewer
// MFMAs and 64 instead of 96 accumulator VGPRs (fits the 84-reg allocation,
// eliminating scratch spill).
DEVI void mfma3(f16x8 ah, f16x8 al, f16x8 bh, f16x8 bl,
                f32x4& acc, f32x4& accx) {
  acc  = mfma16(ah, bh, acc);
  accx = mfma16(ah, bl, accx);
  accx = mfma16(al, bh, accx);
}
DEVI float combine3(float a, float ax, float ay, float b) {
  return (float)((double)a + ((double)ax + (double)ay * LO_INV_D) * LO_INV_D + (double)b);
}
DEVI float combine2(float a, float ax, float b) {
  return (float)((double)a + (double)ax * LO_INV_D + (double)b);
}
// swizzled element offset inside one [rows][128] fp16 tile (row stride 256B).
DEVI int swz(int row, int col) { return row * 128 + (col ^ ((row & 7) << 3)); }

struct KParams {
  const unsigned short* w1h; const unsigned short* w1l;
  const unsigned short* w2h; const unsigned short* w2l;
  const float* b1; const float* b2; const float* g; const float* be;
  const float* srcA;                 // ENC: x/e
  const unsigned short* xhi;         // fp16 hi mirror of xh
  const unsigned short* xlo;         // fp16 lo mirror (x2048)
  float* xf;                         // xh f32 master
  float* ef;                         // eh f32 master
  unsigned short* xhi_out; unsigned short* xlo_out;
  const int* rowi; const int* coli;
  int* aggi;                         // [N,128] int32 2^22 fixed-point aggregate
  float* out;
  const float* w2f; const float* b2f;  // decoder layer-2 (f32)
  int nrows; int kin;
};

struct RepackItem { const float* src; unsigned short* dst; int K; int Kt; };
struct RepackParams { RepackItem it[17]; };

// Pack W [K][128] f32 -> fp16 hi/lo MFMA B-fragments. hi at [0, Kt*8*512),
// lo (x2048) at [Kt*8*512, 2*Kt*8*512).
__global__ __launch_bounds__(256) void repack_kernel(RepackParams rp) {
  const RepackItem w = rp.it[blockIdx.y];
  const int f = blockIdx.x;
  if (f >= w.Kt * 8) return;
  const int kt = f >> 3, nt = f & 7;
  const size_t loOff = (size_t)w.Kt * 8 * 512;
  for (int s = threadIdx.x; s < 512; s += 256) {
    int ln = s >> 3, j = s & 7;
    int k = kt * 32 + ((ln >> 4) << 3) + j;
    int c = nt * 16 + (ln & 15);
    float v = (k < w.K) ? w.src[(size_t)k * 128 + c] : 0.f;
    unsigned short hi = f2h(v);
    w.dst[(size_t)f * 512 + s] = hi;
    w.dst[loOff + (size_t)f * 512 + s] = loPart(v, hi);
  }
}

// ---------------- edge processor (BK=64 staging + 3-term hi/lo GEMM) ----------
// 768 threads (12 waves) over 96 edges; waves 0-5 = msg variant (bands 0-5),
// waves 6-11 = edge-update. Weights staged as PAIRS of 16KB K-steps into a
// 2 x 32KB LDS double-buffer (one barrier per TWO K-steps). LDS = 160KB full
// pool, 3 waves/SIMD. 3-term mfma (acc+accx only): 25% fewer MFMAs and 64
// accumulator VGPRs -> fits the 84-reg allocation, no scratch spill.
__global__ __attribute__((amdgpu_flat_work_group_size(768, 768)))
void edge_kernel(KParams p) {
  constexpr int NT = 768;
  constexpr int REG = 12288;                       // elems per hi (or lo) region
  __shared__ __align__(16) unsigned short stA[2 * 2 * REG];   // h1 hi/lo x 2 variants
  __shared__ __align__(16) unsigned short wbuf[2 * 16384];    // 2 bufs x (2 steps x 8K)

  const int tid = threadIdx.x;
  const int lane = tid & 63;
  const int wave = tid >> 6;
  const int w4 = wave % 6;        // 16-row band index
  const int vrt = wave / 6;       // variant: 0=msg 1=edge-update
  const int r0 = blockIdx.x * 96;
  const int l15 = lane & 15;
  const int lg = lane >> 4;

  auto HI = [&](int t) { return stA + 2 * t * REG; };
  auto LO = [&](int t) { return stA + 2 * t * REG + REG; };

  // stage steps {2*pair, 2*pair+1} (2 x 8192 elems) into wbuf[buf]
  auto stageW2 = [&](int pair, int buf) {
    for (int i = tid; i < 2048; i += NT) {
      const int sub = i >> 10;              // which step of the pair
      const int s = pair * 2 + sub;
      const int j = i & 1023;               // 0..511 hi, 512..1023 lo
      const unsigned short* h = (s < 12) ? p.w1h + s * 4096 : p.w2h + (s - 12) * 4096;
      const unsigned short* l = (s < 12) ? p.w1l + s * 4096 : p.w2l + (s - 12) * 4096;
      *(f16x8*)&wbuf[buf * 16384 + sub * 8192 +
                     ((j < 512) ? j * 8 : 4096 + (j - 512) * 8)] =
          *(const f16x8*)((j < 512) ? h + j * 8 : l + (j - 512) * 8);
    }
  };

  stageW2(0, 0);   // steps 0,1
  __syncthreads();

  // ---------------- layer 1 (K = 12*32, 6 step-pairs) ----------------
  const f32x4 zz = {0.f, 0.f, 0.f, 0.f};
  f32x4 acc1[8], acc1x[8];
#pragma unroll
  for (int nt = 0; nt < 8; nt++) { acc1[nt] = zz; acc1x[nt] = zz; }
  const int arow = w4 * 16 + l15;
  const int acol = lg << 3;

  const int ridx = r0 + arow;
  const int ec = (ridx < p.nrows) ? ridx : 0;   // clamped (outputs discarded)
  const int nc = p.coli[ec], nr = p.rowi[ec];
  // msg variant: [Xc, Xr, Ee] ; edge-update variant: [Xr, Xc, Ee]
  const unsigned short* aH = p.xhi + (size_t)(vrt ? nr : nc) * 128;
  const unsigned short* aL = p.xlo + (size_t)(vrt ? nr : nc) * 128;
  const unsigned short* bH = p.xhi + (size_t)(vrt ? nc : nr) * 128;
  const unsigned short* bL = p.xlo + (size_t)(vrt ? nc : nr) * 128;
  const float* ep = p.ef + (size_t)ec * 128;
#pragma unroll
  for (int pr = 0; pr < 6; pr++) {
    const int cur = pr & 1;
    stageW2(pr + 1, cur ^ 1);   // pairs 1..6 (pair 6 = W2 steps 12,13)
#pragma unroll
    for (int half = 0; half < 2; half++) {
      const int kt = pr * 2 + half;
      const int kc = (kt & 3) * 32 + acol;
      f16x8 ah, al;
      if (kt < 4)      { ah = *(const f16x8*)(aH + kc); al = *(const f16x8*)(aL + kc); }
      else if (kt < 8) { ah = *(const f16x8*)(bH + kc); al = *(const f16x8*)(bL + kc); }
      else {
        union { unsigned short u[8]; f16x8 v; } th, tl;
#pragma unroll
        for (int j = 0; j < 8; j++) {
          float v = ep[kc + j];
          th.u[j] = f2h(v); tl.u[j] = loPart(v, th.u[j]);
        }
        ah = th.v; al = tl.v;
      }
#pragma unroll
      for (int nt = 0; nt < 8; nt++) {
        f16x8 bh = *(const f16x8*)&wbuf[cur * 16384 + half * 8192 + nt * 512 + lane * 8];
        f16x8 bl = *(const f16x8*)&wbuf[cur * 16384 + half * 8192 + 4096 + nt * 512 + lane * 8];
        mfma3(ah, al, bh, bl, acc1[nt], acc1x[nt]);
      }
    }
    __syncthreads();
  }

  // ---------------- h1 = relu(acc + b1) -> LDS hi/lo (region vrt) ----------
  // Each wave writes/reads only its own 16-row band (in-order per wave).
  float b1c[8];
#pragma unroll
  for (int nt = 0; nt < 8; nt++) b1c[nt] = p.b1[nt * 16 + l15];
#pragma unroll
  for (int nt = 0; nt < 8; nt++) {
#pragma unroll
    for (int r = 0; r < 4; r++) {
      int row = w4 * 16 + (lg << 2) + r;
      int col = nt * 16 + l15;
      int off = swz(row, col);
      float v = combine2(acc1[nt][r], acc1x[nt][r], b1c[nt]);
      v = v > 0.f ? v : 0.f;
      unsigned short hi = f2h(v);
      HI(vrt)[off] = hi; LO(vrt)[off] = loPart(v, hi);
    }
  }

  // ---------------- layer 2 (K=128, 2 step-pairs; pair 6 = buf0) ----------
  f32x4 acc2[8], acc2x[8];
#pragma unroll
  for (int nt = 0; nt < 8; nt++) { acc2[nt] = zz; acc2x[nt] = zz; }
#pragma unroll
  for (int pr = 6; pr < 8; pr++) {
    const int cur = pr & 1;
    if (pr == 6) stageW2(7, 1);   // W2 steps 14,15 -> buf1
#pragma unroll
    for (int half = 0; half < 2; half++) {
      const int kt2 = (pr - 6) * 2 + half;   // 0..3
      int so = swz(arow, kt2 * 32 + acol);
      f16x8 ah = *(const f16x8*)&HI(vrt)[so];
      f16x8 al = *(const f16x8*)&LO(vrt)[so];
#pragma unroll
      for (int nt = 0; nt < 8; nt++) {
        f16x8 bh = *(const f16x8*)&wbuf[cur * 16384 + half * 8192 + nt * 512 + lane * 8];
        f16x8 bl = *(const f16x8*)&wbuf[cur * 16384 + half * 8192 + 4096 + nt * 512 + lane * 8];
        mfma3(ah, al, bh, bl, acc2[nt], acc2x[nt]);
      }
    }
    if (pr == 6) __syncthreads();
  }

  // ---------------- LayerNorm epilogue (f64 statistics) ----------------
  float b2c[8], gc[8], bec[8];
#pragma unroll
  for (int nt = 0; nt < 8; nt++) {
    int c = nt * 16 + l15;
    b2c[nt] = p.b2[c]; gc[nt] = p.g[c]; bec[nt] = p.be[c];
  }
  {
    double sum[4] = {0.0, 0.0, 0.0, 0.0};
#pragma unroll
    for (int nt = 0; nt < 8; nt++)
#pragma unroll
      for (int r = 0; r < 4; r++) {
        acc2[nt][r] = combine2(acc2[nt][r], acc2x[nt][r], b2c[nt]);
        sum[r] += (double)acc2[nt][r];
      }
#pragma unroll
    for (int r = 0; r < 4; r++) {
#pragma unroll
      for (int m = 1; m < 16; m <<= 1) sum[r] += __shfl_xor(sum[r], m);
      sum[r] *= (1.0 / 128.0);
    }
    double vs[4] = {0.0, 0.0, 0.0, 0.0};
#pragma unroll
    for (int nt = 0; nt < 8; nt++)
#pragma unroll
      for (int r = 0; r < 4; r++) {
        double d = (double)acc2[nt][r] - sum[r];
        vs[r] += d * d;
      }
#pragma unroll
    for (int r = 0; r < 4; r++) {
#pragma unroll
      for (int m = 1; m < 16; m <<= 1) vs[r] += __shfl_xor(vs[r], m);
      vs[r] = 1.0 / sqrt(vs[r] * (1.0 / 128.0) + 1e-5);
    }
#pragma unroll
    for (int nt = 0; nt < 8; nt++)
#pragma unroll
      for (int r = 0; r < 4; r++)
        acc2[nt][r] = (float)(((double)acc2[nt][r] - sum[r]) * vs[r]) * gc[nt] + bec[nt];
  }

  // order all ef reads (layer 1) before variant-1's in-place ef writes below.
  __syncthreads();

  // ---------------- writeback ----------------
#pragma unroll
  for (int r = 0; r < 4; r++) {
    int idx = r0 + w4 * 16 + (lg << 2) + r;
    if (idx >= p.nrows) continue;
    if (vrt == 0) {
      int tgt = p.coli[idx];
      int* ar = p.aggi + (size_t)tgt * 128;
#pragma unroll
      for (int nt = 0; nt < 8; nt++) {
        int q = __double2int_rn((double)acc2[nt][r] * AGG_SCALE_D);
        atomicAdd(&ar[nt * 16 + l15], q);
      }
    } else {
      float* er = p.ef + (size_t)idx * 128;
#pragma unroll
      for (int nt = 0; nt < 8; nt++) {
        int c = nt * 16 + l15;
        er[c] = acc2[nt][r] + er[c];
      }
    }
  }
}

// Modes: 0=node-encoder 1=edge-encoder 3=node-processor 4=decoder
template <int MODE>
__global__ __launch_bounds__(256, 2)
void gnn_kernel(KParams p) {
  constexpr int NT = 256;
  constexpr int REG = 8192;                        // elems per hi (or lo) region
  constexpr int NREG = (MODE == 3) ? 2 : 1;
  __shared__ __align__(16) unsigned short stA[NREG * 2 * REG];
  __shared__ float w2s[(MODE == 4) ? 392 : 1];

  const int tid = threadIdx.x;
  const int lane = tid & 63;
  const int wave = tid >> 6;
  const int w4 = wave;            // 16-row band index
  const int r0 = blockIdx.x * 64;
  const int l15 = lane & 15;
  const int lg = lane >> 4;

  auto HI = [&](int t) { return stA + 2 * t * REG; };
  auto LO = [&](int t) { return stA + 2 * t * REG + REG; };

  // ---------------- stage inputs (fp16 hi/lo, swizzled) ----------------
  if constexpr (MODE == 3) {
    for (int s = tid; s < 1024; s += NT) {
      int row = s >> 4, cc = (s & 15) * 8;
      int n = r0 + row;
      int off = swz(row, cc);
      if (n < p.nrows) {
        const int* ap = p.aggi + (size_t)n * 128 + cc;
        union { unsigned short u[8]; f16x8 v; } th, tl;
#pragma unroll
        for (int j = 0; j < 8; j++) {
          float v = (float)((double)ap[j] * AGG_INV_D);   // exact int->double->f32
          th.u[j] = f2h(v); tl.u[j] = loPart(v, th.u[j]);
        }
        *(f16x8*)&HI(0)[off] = th.v; *(f16x8*)&LO(0)[off] = tl.v;
        *(f16x8*)&HI(1)[off] = *(const f16x8*)(p.xhi + (size_t)n * 128 + cc);
        *(f16x8*)&LO(1)[off] = *(const f16x8*)(p.xlo + (size_t)n * 128 + cc);
      } else {
        f16x8 z = {0,0,0,0,0,0,0,0};
        *(f16x8*)&HI(0)[off] = z; *(f16x8*)&LO(0)[off] = z;
        *(f16x8*)&HI(1)[off] = z; *(f16x8*)&LO(1)[off] = z;
      }
    }
  } else if constexpr (MODE == 0 || MODE == 1) {
    for (int s = tid; s < 256; s += NT) {
      int row = s >> 2, cc = (s & 3) * 8;
      int n = r0 + row;
      union { unsigned short u[8]; f16x8 v; } th, tl;
#pragma unroll
      for (int j = 0; j < 8; j++) {
        int k = cc + j;
        float v = (n < p.nrows && k < p.kin) ? p.srcA[(size_t)n * p.kin + k] : 0.f;
        th.u[j] = f2h(v); tl.u[j] = loPart(v, th.u[j]);
      }
      int off = swz(row, cc);
      *(f16x8*)&HI(0)[off] = th.v; *(f16x8*)&LO(0)[off] = tl.v;
    }
  } else if constexpr (MODE == 4) {
    for (int s = tid; s < 1024; s += NT) {
      int row = s >> 4, cc = (s & 15) * 8;
      int n = r0 + row;
      int off = swz(row, cc);
      f16x8 z = {0,0,0,0,0,0,0,0};
      if (n < p.nrows) {
        *(f16x8*)&HI(0)[off] = *(const f16x8*)(p.xhi + (size_t)n * 128 + cc);
        *(f16x8*)&LO(0)[off] = *(const f16x8*)(p.xlo + (size_t)n * 128 + cc);
      } else { *(f16x8*)&HI(0)[off] = z; *(f16x8*)&LO(0)[off] = z; }
    }
    for (int s = tid; s < 387; s += NT) w2s[s] = (s < 384) ? p.w2f[s] : p.b2f[s - 384];
  }
  __syncthreads();

  // ---------------- layer 1 (K = K1T*32) ----------------
  constexpr int K1T = (MODE == 3) ? 8 : (MODE == 4) ? 4 : 1;
  const f32x4 zz = {0.f, 0.f, 0.f, 0.f};
  f32x4 acc1[8], acc1x[8], acc1y[8];
#pragma unroll
  for (int nt = 0; nt < 8; nt++) { acc1[nt] = zz; acc1x[nt] = zz; acc1y[nt] = zz; }
  const int arow = w4 * 16 + l15;
  const int acol = lg << 3;

#pragma unroll
  for (int kt = 0; kt < K1T; kt++) {
    int t = kt >> 2;
    int so = swz(arow, (kt & 3) * 32 + acol);
    f16x8 ah = *(const f16x8*)&HI(t)[so];
    f16x8 al = *(const f16x8*)&LO(t)[so];
#pragma unroll
    for (int nt = 0; nt < 8; nt++) {
      f16x8 bh = *(const f16x8*)&p.w1h[(size_t)(kt * 8 + nt) * 512 + lane * 8];
      f16x8 bl = *(const f16x8*)&p.w1l[(size_t)(kt * 8 + nt) * 512 + lane * 8];
      mfma4(ah, al, bh, bl, acc1[nt], acc1x[nt], acc1y[nt]);
    }
  }

  // ---------------- h1 = relu(acc + b1) -> LDS hi/lo (region 0) ----------
  float b1c[8];
#pragma unroll
  for (int nt = 0; nt < 8; nt++) b1c[nt] = p.b1[nt * 16 + l15];
#pragma unroll
  for (int nt = 0; nt < 8; nt++) {
#pragma unroll
    for (int r = 0; r < 4; r++) {
      int row = w4 * 16 + (lg << 2) + r;
      int col = nt * 16 + l15;
      int off = swz(row, col);
      float v = combine3(acc1[nt][r], acc1x[nt][r], acc1y[nt][r], b1c[nt]);
      v = v > 0.f ? v : 0.f;
      unsigned short hi = f2h(v);
      HI(0)[off] = hi; LO(0)[off] = loPart(v, hi);
    }
  }

  if constexpr (MODE != 4) {
    // ---------------- layer 2 (K=128 from h1 in LDS) ----------------
    f32x4 acc2[8], acc2x[8], acc2y[8];
#pragma unroll
    for (int nt = 0; nt < 8; nt++) { acc2[nt] = zz; acc2x[nt] = zz; acc2y[nt] = zz; }
#pragma unroll
    for (int kt = 0; kt < 4; kt++) {
      int so = swz(arow, kt * 32 + acol);
      f16x8 ah = *(const f16x8*)&HI(0)[so];
      f16x8 al = *(const f16x8*)&LO(0)[so];
#pragma unroll
      for (int nt = 0; nt < 8; nt++) {
        f16x8 bh = *(const f16x8*)&p.w2h[(size_t)(kt * 8 + nt) * 512 + lane * 8];
        f16x8 bl = *(const f16x8*)&p.w2l[(size_t)(kt * 8 + nt) * 512 + lane * 8];
        mfma4(ah, al, bh, bl, acc2[nt], acc2x[nt], acc2y[nt]);
      }
    }

    // ---------------- LayerNorm epilogue (f64 statistics) ----------------
    float b2c[8], gc[8], bec[8];
#pragma unroll
    for (int nt = 0; nt < 8; nt++) {
      int c = nt * 16 + l15;
      b2c[nt] = p.b2[c]; gc[nt] = p.g[c]; bec[nt] = p.be[c];
    }
    {
      double sum[4] = {0.0, 0.0, 0.0, 0.0};
#pragma unroll
      for (int nt = 0; nt < 8; nt++)
#pragma unroll
        for (int r = 0; r < 4; r++) {
          acc2[nt][r] = combine3(acc2[nt][r], acc2x[nt][r], acc2y[nt][r], b2c[nt]);
          sum[r] += (double)acc2[nt][r];
        }
#pragma unroll
      for (int r = 0; r < 4; r++) {
#pragma unroll
        for (int m = 1; m < 16; m <<= 1) sum[r] += __shfl_xor(sum[r], m);
        sum[r] *= (1.0 / 128.0);
      }
      double vs[4] = {0.0, 0.0, 0.0, 0.0};
#pragma unroll
      for (int nt = 0; nt < 8; nt++)
#pragma unroll
        for (int r = 0; r < 4; r++) {
          double d = (double)acc2[nt][r] - sum[r];
          vs[r] += d * d;
        }
#pragma unroll
      for (int r = 0; r < 4; r++) {
#pragma unroll
        for (int m = 1; m < 16; m <<= 1) vs[r] += __shfl_xor(vs[r], m);
        vs[r] = 1.0 / sqrt(vs[r] * (1.0 / 128.0) + 1e-5);
      }
#pragma unroll
      for (int nt = 0; nt < 8; nt++)
#pragma unroll
        for (int r = 0; r < 4; r++)
          acc2[nt][r] = (float)(((double)acc2[nt][r] - sum[r]) * vs[r]) * gc[nt] + bec[nt];
    }

    // ---------------- writeback ----------------
#pragma unroll
    for (int r = 0; r < 4; r++) {
      int idx = r0 + w4 * 16 + (lg << 2) + r;
      if (idx >= p.nrows) continue;
      if constexpr (MODE == 0) {
        float* xr = p.xf + (size_t)idx * 128;
        unsigned short* xh_ = p.xhi_out + (size_t)idx * 128;
        unsigned short* xl_ = p.xlo_out + (size_t)idx * 128;
#pragma unroll
        for (int nt = 0; nt < 8; nt++) {
          int c = nt * 16 + l15; float v = acc2[nt][r];
          xr[c] = v;
          unsigned short hi = f2h(v);
          xh_[c] = hi; xl_[c] = loPart(v, hi);
        }
      } else if constexpr (MODE == 1) {
        float* er = p.ef + (size_t)idx * 128;
#pragma unroll
        for (int nt = 0; nt < 8; nt++) er[nt * 16 + l15] = acc2[nt][r];
      } else {  // MODE 3
        float* xr = p.xf + (size_t)idx * 128;
        unsigned short* xh_ = p.xhi_out + (size_t)idx * 128;
        unsigned short* xl_ = p.xlo_out + (size_t)idx * 128;
#pragma unroll
        for (int nt = 0; nt < 8; nt++) {
          int c = nt * 16 + l15;
          float v = acc2[nt][r] + xr[c];   // residual from f32 master
          xr[c] = v;
          unsigned short hi = f2h(v);
          xh_[c] = hi; xl_[c] = loPart(v, hi);
        }
      }
    }
  } else {
    // ---------------- decoder tail: out = h1 @ w2f + b2 (OUT=3, f64 acc) -----
    __syncthreads();   // tail reads h1 rows written by other waves
    if (tid < 192) {
      int row = tid / 3, oc = tid - row * 3;
      int n = r0 + row;
      if (n < p.nrows) {
        double s = (double)w2s[384 + oc];
        for (int k = 0; k < 128; k++) {
          int off = swz(row, k);
          double h = (double)h2f(HI(0)[off]) + (double)h2f(LO(0)[off]) * LO_INV_D;
          s += h * (double)w2s[k * 3 + oc];
        }
        p.out[(size_t)n * 3 + oc] = (float)s;
      }
    }
  }
}

extern "C" void kernel_launch(void* const* d_in, const int* in_sizes, int n_in,
                              void* d_out, int out_size, void* d_ws, size_t ws_size,
                              hipStream_t stream) {
  if (n_in < 31) return;
  const int N = in_sizes[0] / 15;
  const int E = in_sizes[1] / 7;
  const float* x        = (const float*)d_in[0];
  const float* ein      = (const float*)d_in[1];
  const int*   eidx     = (const int*)d_in[2];
  const float* enc_n_w1 = (const float*)d_in[3];
  const float* enc_n_b1 = (const float*)d_in[4];
  const float* enc_n_w2 = (const float*)d_in[5];
  const float* enc_n_b2 = (const float*)d_in[6];
  const float* enc_n_g  = (const float*)d_in[7];
  const float* enc_n_be = (const float*)d_in[8];
  const float* enc_e_w1 = (const float*)d_in[9];
  const float* enc_e_b1 = (const float*)d_in[10];
  const float* enc_e_w2 = (const float*)d_in[11];
  const float* enc_e_b2 = (const float*)d_in[12];
  const float* enc_e_g  = (const float*)d_in[13];
  const float* enc_e_be = (const float*)d_in[14];
  const float* pe_w1    = (const float*)d_in[15];
  const float* pe_b1    = (const float*)d_in[16];
  const float* pe_w2    = (const float*)d_in[17];
  const float* pe_b2    = (const float*)d_in[18];
  const float* pe_g     = (const float*)d_in[19];
  const float* pe_be    = (const float*)d_in[20];
  const float* pn_w1    = (const float*)d_in[21];
  const float* pn_b1    = (const float*)d_in[22];
  const float* pn_w2    = (const float*)d_in[23];
  const float* pn_b2    = (const float*)d_in[24];
  const float* pn_g     = (const float*)d_in[25];
  const float* pn_be    = (const float*)d_in[26];
  const float* dec_w1   = (const float*)d_in[27];
  const float* dec_b1   = (const float*)d_in[28];
  const float* dec_w2   = (const float*)d_in[29];
  const float* dec_b2   = (const float*)d_in[30];

  char* ws = (char*)d_ws;
  size_t off = 0;
  auto carve = [&](size_t bytes) -> void* {
    void* pp = ws + off; off += (bytes + 255) & ~(size_t)255; return pp;
  };
  float* xh            = (float*)carve((size_t)N * 128 * 4);
  unsigned short* xhi  = (unsigned short*)carve((size_t)N * 128 * 2);
  unsigned short* xlo  = (unsigned short*)carve((size_t)N * 128 * 2);
  float* eh            = (float*)carve((size_t)E * 128 * 4);
  int* aggi            = (int*)carve((size_t)N * 128 * 4);

  const int ktab[17] = {15, 128, 7, 128, 384, 384, 384, 128, 128, 128,
                        256, 256, 256, 128, 128, 128, 128};
  unsigned short* pk[17];
  for (int i = 0; i < 17; i++) {
    int kt = (ktab[i] + 31) / 32;
    pk[i] = (unsigned short*)carve((size_t)2 * kt * 8 * 512 * 2);  // hi+lo
  }
  if (off > ws_size) return;  // workspace too small -> fail validation loudly

  RepackParams rp;
  const float* wsrc[17] = {enc_n_w1, enc_n_w2, enc_e_w1, enc_e_w2,
                           pe_w1, pe_w1 + 384 * 128, pe_w1 + 2 * 384 * 128,
                           pe_w2, pe_w2 + 128 * 128, pe_w2 + 2 * 128 * 128,
                           pn_w1, pn_w1 + 256 * 128, pn_w1 + 2 * 256 * 128,
                           pn_w2, pn_w2 + 128 * 128, pn_w2 + 2 * 128 * 128,
                           dec_w1};
  for (int i = 0; i < 17; i++) {
    rp.it[i].src = wsrc[i]; rp.it[i].dst = pk[i];
    rp.it[i].K = ktab[i]; rp.it[i].Kt = (ktab[i] + 31) / 32;
  }
  repack_kernel<<<dim3(96, 17), 256, 0, stream>>>(rp);

  auto wlo = [&](int i) { return pk[i] + (size_t)((ktab[i] + 31) / 32) * 8 * 512; };
  const int gN = (N + 63) / 64, gE = (E + 63) / 64, gE96 = (E + 95) / 96;

  {  // node encoder
    KParams kp{};
    kp.w1h = pk[0]; kp.w1l = wlo(0); kp.w2h = pk[1]; kp.w2l = wlo(1);
    kp.b1 = enc_n_b1; kp.b2 = enc_n_b2; kp.g = enc_n_g; kp.be = enc_n_be;
    kp.srcA = x; kp.xf = xh; kp.xhi_out = xhi; kp.xlo_out = xlo;
    kp.nrows = N; kp.kin = 15;
    gnn_kernel<0><<<gN, 256, 0, stream>>>(kp);
  }
  {  // edge encoder
    KParams kp{};
    kp.w1h = pk[2]; kp.w1l = wlo(2); kp.w2h = pk[3]; kp.w2l = wlo(3);
    kp.b1 = enc_e_b1; kp.b2 = enc_e_b2; kp.g = enc_e_g; kp.be = enc_e_be;
    kp.srcA = ein; kp.ef = eh; kp.nrows = E; kp.kin = 7;
    gnn_kernel<1><<<gE, 256, 0, stream>>>(kp);
  }
  for (int i = 0; i < 3; i++) {
    hipMemsetAsync(aggi, 0, (size_t)N * 128 * 4, stream);
    {  // edge processor (768 threads: 6 msg waves + 6 edge-update waves)
      KParams kp{};
      kp.w1h = pk[4 + i]; kp.w1l = wlo(4 + i);
      kp.w2h = pk[7 + i]; kp.w2l = wlo(7 + i);
      kp.b1 = pe_b1 + i * 128; kp.b2 = pe_b2 + i * 128;
      kp.g = pe_g + i * 128; kp.be = pe_be + i * 128;
      kp.xhi = xhi; kp.xlo = xlo; kp.ef = eh;
      kp.rowi = eidx; kp.coli = eidx + E;
      kp.aggi = aggi; kp.nrows = E;
      edge_kernel<<<gE96, 768, 0, stream>>>(kp);
    }
    {  // node processor (reads deterministic int32 aggregate via double)
      KParams kp{};
      kp.w1h = pk[10 + i]; kp.w1l = wlo(10 + i);
      kp.w2h = pk[13 + i]; kp.w2l = wlo(13 + i);
      kp.b1 = pn_b1 + i * 128; kp.b2 = pn_b2 + i * 128;
      kp.g = pn_g + i * 128; kp.be = pn_be + i * 128;
      kp.aggi = aggi; kp.xhi = xhi; kp.xlo = xlo;
      kp.xf = xh; kp.xhi_out = xhi; kp.xlo_out = xlo; kp.nrows = N;
      gnn_kernel<3><<<gN, 256, 0, stream>>>(kp);
    }
  }
  {  // decoder
    KParams kp{};
    kp.w1h = pk[16]; kp.w1l = wlo(16); kp.b1 = dec_b1;
    kp.xhi = xhi; kp.xlo = xlo; kp.w2f = dec_w2; kp.b2f = dec_b2;
    kp.out = (float*)d_out; kp.nrows = N;
    gnn_kernel<4><<<gN, 256, 0, stream>>>(kp);
  }
}